// Round 1
// baseline (19985.133 us; speedup 1.0000x reference)
//
#include <hip/hip_runtime.h>
#include <math.h>

// softplus(x) = log1p(exp(x)) = max(x,0) + log1p(exp(-|x|))
__device__ __forceinline__ float sp_f(float x) {
  return fmaxf(x, 0.0f) + log1pf(__expf(-fabsf(x)));
}

// ---------------- node embedding: x[N,92] (+charge emb) @ W_atom[108,64] ----------------
__global__ __launch_bounds__(256) void k_embed_nodes(
    const float* __restrict__ x, const int* __restrict__ batch,
    const float* __restrict__ charge, const float* __restrict__ W_charge,
    const float* __restrict__ b_charge, const float* __restrict__ W_atom,
    const float* __restrict__ b_atom, float* __restrict__ xemb, int N) {
  __shared__ float sW[108 * 64];
  __shared__ float sb[64];
  __shared__ float sWc[16];
  __shared__ float sbc[16];
  for (int i = threadIdx.x; i < 108 * 64; i += blockDim.x) sW[i] = W_atom[i];
  if (threadIdx.x < 64) sb[threadIdx.x] = b_atom[threadIdx.x];
  if (threadIdx.x < 16) {
    sWc[threadIdx.x] = W_charge[threadIdx.x];
    sbc[threadIdx.x] = b_charge[threadIdx.x];
  }
  __syncthreads();
  int stride = gridDim.x * blockDim.x;
  for (int n = blockIdx.x * blockDim.x + threadIdx.x; n < N; n += stride) {
    float acc[64];
#pragma unroll
    for (int j = 0; j < 64; ++j) acc[j] = sb[j];
    const float* xr = x + (size_t)n * 92;
    for (int k = 0; k < 92; ++k) {
      float a = xr[k];
      const float* w = sW + k * 64;
#pragma unroll
      for (int j = 0; j < 64; ++j) acc[j] = fmaf(a, w[j], acc[j]);
    }
    float ch = charge[batch[n]];
#pragma unroll
    for (int c = 0; c < 16; ++c) {
      float cf = fmaf(ch, sWc[c], sbc[c]);
      const float* w = sW + (92 + c) * 64;
#pragma unroll
      for (int j = 0; j < 64; ++j) acc[j] = fmaf(cf, w[j], acc[j]);
    }
    float* o = xemb + (size_t)n * 64;
#pragma unroll
    for (int q = 0; q < 16; ++q)
      ((float4*)o)[q] = make_float4(acc[4*q], acc[4*q+1], acc[4*q+2], acc[4*q+3]);
  }
}

// ---------------- bond embedding: edge_attr[E,41] @ W_bond[41,64] ----------------
__global__ __launch_bounds__(256) void k_embed_bonds(
    const float* __restrict__ eattr, const float* __restrict__ W_bond,
    const float* __restrict__ b_bond, float* __restrict__ ea, int E) {
  __shared__ float sW[41 * 64];
  __shared__ float sb[64];
  for (int i = threadIdx.x; i < 41 * 64; i += blockDim.x) sW[i] = W_bond[i];
  if (threadIdx.x < 64) sb[threadIdx.x] = b_bond[threadIdx.x];
  __syncthreads();
  int stride = gridDim.x * blockDim.x;
  for (int e = blockIdx.x * blockDim.x + threadIdx.x; e < E; e += stride) {
    float acc[64];
#pragma unroll
    for (int j = 0; j < 64; ++j) acc[j] = sb[j];
    const float* er = eattr + (size_t)e * 41;
    for (int k = 0; k < 41; ++k) {
      float a = er[k];
      const float* w = sW + k * 64;
#pragma unroll
      for (int j = 0; j < 64; ++j) acc[j] = fmaf(a, w[j], acc[j]);
    }
    float* o = ea + (size_t)e * 64;
#pragma unroll
    for (int q = 0; q < 16; ++q)
      ((float4*)o)[q] = make_float4(acc[4*q], acc[4*q+1], acc[4*q+2], acc[4*q+3]);
  }
}

// ---------------- per-layer node-side precompute: u = x@W1a, p = x@nW1a, v = x@W1b ----------------
__global__ __launch_bounds__(256) void k_node_pre(
    const float* __restrict__ xemb, const float* __restrict__ eW1,
    const float* __restrict__ nW1, float* __restrict__ up,
    float* __restrict__ vbuf, int N) {
  __shared__ float sWa[64 * 64];  // eW1 rows 0..63   (x_row)
  __shared__ float sWb[64 * 64];  // eW1 rows 64..127 (x_col)
  __shared__ float sWp[64 * 64];  // nW1 rows 0..63   (x_row)
  for (int i = threadIdx.x; i < 64 * 64; i += blockDim.x) {
    sWa[i] = eW1[i];
    sWb[i] = eW1[64 * 64 + i];
    sWp[i] = nW1[i];
  }
  __syncthreads();
  int stride = gridDim.x * blockDim.x;
  for (int n = blockIdx.x * blockDim.x + threadIdx.x; n < N; n += stride) {
    const float4* xr4 = (const float4*)(xemb + (size_t)n * 64);
    float u[64], p[64];
#pragma unroll
    for (int j = 0; j < 64; ++j) { u[j] = 0.f; p[j] = 0.f; }
    for (int k4 = 0; k4 < 16; ++k4) {
      float4 av = xr4[k4];
      const float* wa = sWa + k4 * 256;
      const float* wp = sWp + k4 * 256;
#pragma unroll
      for (int j = 0; j < 64; ++j) u[j] = fmaf(av.x, wa[j], u[j]);
#pragma unroll
      for (int j = 0; j < 64; ++j) p[j] = fmaf(av.x, wp[j], p[j]);
#pragma unroll
      for (int j = 0; j < 64; ++j) u[j] = fmaf(av.y, wa[64 + j], u[j]);
#pragma unroll
      for (int j = 0; j < 64; ++j) p[j] = fmaf(av.y, wp[64 + j], p[j]);
#pragma unroll
      for (int j = 0; j < 64; ++j) u[j] = fmaf(av.z, wa[128 + j], u[j]);
#pragma unroll
      for (int j = 0; j < 64; ++j) p[j] = fmaf(av.z, wp[128 + j], p[j]);
#pragma unroll
      for (int j = 0; j < 64; ++j) u[j] = fmaf(av.w, wa[192 + j], u[j]);
#pragma unroll
      for (int j = 0; j < 64; ++j) p[j] = fmaf(av.w, wp[192 + j], p[j]);
    }
    float* o = up + (size_t)n * 128;
#pragma unroll
    for (int q = 0; q < 16; ++q)
      ((float4*)o)[q] = make_float4(u[4*q], u[4*q+1], u[4*q+2], u[4*q+3]);
#pragma unroll
    for (int q = 0; q < 16; ++q)
      ((float4*)(o + 64))[q] = make_float4(p[4*q], p[4*q+1], p[4*q+2], p[4*q+3]);
    // second pass: v = x @ W1b
    float vv[64];
#pragma unroll
    for (int j = 0; j < 64; ++j) vv[j] = 0.f;
    for (int k4 = 0; k4 < 16; ++k4) {
      float4 av = xr4[k4];
      const float* wb = sWb + k4 * 256;
#pragma unroll
      for (int j = 0; j < 64; ++j) vv[j] = fmaf(av.x, wb[j], vv[j]);
#pragma unroll
      for (int j = 0; j < 64; ++j) vv[j] = fmaf(av.y, wb[64 + j], vv[j]);
#pragma unroll
      for (int j = 0; j < 64; ++j) vv[j] = fmaf(av.z, wb[128 + j], vv[j]);
#pragma unroll
      for (int j = 0; j < 64; ++j) vv[j] = fmaf(av.w, wb[192 + j], vv[j]);
    }
    float* ov = vbuf + (size_t)n * 64;
#pragma unroll
    for (int q = 0; q < 16; ++q)
      ((float4*)ov)[q] = make_float4(vv[4*q], vv[4*q+1], vv[4*q+2], vv[4*q+3]);
  }
}

// ---------------- fused per-layer edge kernel ----------------
// t   = sp(eb1 + u[row] + v[col] + ea@W1c)        (hidden1)
// ea' = t @ eW2 + eb2                              (stored)
// t2  = sp(nb1 + p[row] + ea'@nW1b)                (hidden2)
// msg = t2 @ nW2 + nb2 ; atomicAdd into xnew[col]
__global__ __launch_bounds__(256) void k_edge(
    const int* __restrict__ row, const int* __restrict__ col,
    const float* __restrict__ up, const float* __restrict__ vbuf,
    float* __restrict__ ea, const float* __restrict__ W1c,
    const float* __restrict__ eb1, const float* __restrict__ eW2,
    const float* __restrict__ eb2, const float* __restrict__ nW1b,
    const float* __restrict__ nb1, const float* __restrict__ nW2,
    const float* __restrict__ nb2, float* __restrict__ xnew, int E) {
  __shared__ float sW1[64 * 64];
  __shared__ float sW2[64 * 64];
  __shared__ float sW3[64 * 64];
  __shared__ float sW4[64 * 64];
  __shared__ float sb1[64], sb2[64], sb3[64], sb4[64];
  __shared__ __align__(16) float s_act[256 * 68];
  for (int i = threadIdx.x; i < 64 * 64; i += blockDim.x) {
    sW1[i] = W1c[i];
    sW2[i] = eW2[i];
    sW3[i] = nW1b[i];
    sW4[i] = nW2[i];
  }
  if (threadIdx.x < 64) {
    sb1[threadIdx.x] = eb1[threadIdx.x];
    sb2[threadIdx.x] = eb2[threadIdx.x];
    sb3[threadIdx.x] = nb1[threadIdx.x];
    sb4[threadIdx.x] = nb2[threadIdx.x];
  }
  __syncthreads();
  float* act = s_act + (size_t)threadIdx.x * 68;
  int stride = gridDim.x * blockDim.x;
  for (int e = blockIdx.x * blockDim.x + threadIdx.x; e < E; e += stride) {
    int r = row[e];
    int c = col[e];
    const float4* u4 = (const float4*)(up + (size_t)r * 128);
    const float4* p4 = u4 + 16;
    const float4* v4 = (const float4*)(vbuf + (size_t)c * 64);
    const float4* e4 = (const float4*)(ea + (size_t)e * 64);

    // ---- phase 1: t = eb1 + ea@W1c + u + v, softplus ----
    float t[64];
#pragma unroll
    for (int j = 0; j < 64; ++j) t[j] = sb1[j];
    for (int k4 = 0; k4 < 16; ++k4) {
      float4 av = e4[k4];
      const float* w = sW1 + k4 * 256;
#pragma unroll
      for (int j = 0; j < 64; ++j) t[j] = fmaf(av.x, w[j], t[j]);
#pragma unroll
      for (int j = 0; j < 64; ++j) t[j] = fmaf(av.y, w[64 + j], t[j]);
#pragma unroll
      for (int j = 0; j < 64; ++j) t[j] = fmaf(av.z, w[128 + j], t[j]);
#pragma unroll
      for (int j = 0; j < 64; ++j) t[j] = fmaf(av.w, w[192 + j], t[j]);
    }
#pragma unroll
    for (int q = 0; q < 16; ++q) {
      float4 uu = u4[q];
      float4 vv = v4[q];
      t[4*q+0] += uu.x + vv.x;
      t[4*q+1] += uu.y + vv.y;
      t[4*q+2] += uu.z + vv.z;
      t[4*q+3] += uu.w + vv.w;
    }
#pragma unroll
    for (int j = 0; j < 64; ++j) t[j] = sp_f(t[j]);
#pragma unroll
    for (int q = 0; q < 16; ++q)
      ((float4*)act)[q] = make_float4(t[4*q], t[4*q+1], t[4*q+2], t[4*q+3]);

    // ---- phase 2: ea' = hidden @ eW2 + eb2 ----
    float en[64];
#pragma unroll
    for (int j = 0; j < 64; ++j) en[j] = sb2[j];
    for (int k4 = 0; k4 < 16; ++k4) {
      float4 av = ((const float4*)act)[k4];
      const float* w = sW2 + k4 * 256;
#pragma unroll
      for (int j = 0; j < 64; ++j) en[j] = fmaf(av.x, w[j], en[j]);
#pragma unroll
      for (int j = 0; j < 64; ++j) en[j] = fmaf(av.y, w[64 + j], en[j]);
#pragma unroll
      for (int j = 0; j < 64; ++j) en[j] = fmaf(av.z, w[128 + j], en[j]);
#pragma unroll
      for (int j = 0; j < 64; ++j) en[j] = fmaf(av.w, w[192 + j], en[j]);
    }
    float* eo = ea + (size_t)e * 64;
#pragma unroll
    for (int q = 0; q < 16; ++q)
      ((float4*)eo)[q] = make_float4(en[4*q], en[4*q+1], en[4*q+2], en[4*q+3]);
#pragma unroll
    for (int q = 0; q < 16; ++q)
      ((float4*)act)[q] = make_float4(en[4*q], en[4*q+1], en[4*q+2], en[4*q+3]);

    // ---- phase 3: t2 = sp(nb1 + p + ea'@nW1b) ----
    float t2[64];
#pragma unroll
    for (int j = 0; j < 64; ++j) t2[j] = sb3[j];
    for (int k4 = 0; k4 < 16; ++k4) {
      float4 av = ((const float4*)act)[k4];
      const float* w = sW3 + k4 * 256;
#pragma unroll
      for (int j = 0; j < 64; ++j) t2[j] = fmaf(av.x, w[j], t2[j]);
#pragma unroll
      for (int j = 0; j < 64; ++j) t2[j] = fmaf(av.y, w[64 + j], t2[j]);
#pragma unroll
      for (int j = 0; j < 64; ++j) t2[j] = fmaf(av.z, w[128 + j], t2[j]);
#pragma unroll
      for (int j = 0; j < 64; ++j) t2[j] = fmaf(av.w, w[192 + j], t2[j]);
    }
#pragma unroll
    for (int q = 0; q < 16; ++q) {
      float4 pp = p4[q];
      t2[4*q+0] += pp.x;
      t2[4*q+1] += pp.y;
      t2[4*q+2] += pp.z;
      t2[4*q+3] += pp.w;
    }
#pragma unroll
    for (int j = 0; j < 64; ++j) t2[j] = sp_f(t2[j]);
#pragma unroll
    for (int q = 0; q < 16; ++q)
      ((float4*)act)[q] = make_float4(t2[4*q], t2[4*q+1], t2[4*q+2], t2[4*q+3]);

    // ---- phase 4: msg = t2 @ nW2 + nb2 ; scatter ----
    float msg[64];
#pragma unroll
    for (int j = 0; j < 64; ++j) msg[j] = sb4[j];
    for (int k4 = 0; k4 < 16; ++k4) {
      float4 av = ((const float4*)act)[k4];
      const float* w = sW4 + k4 * 256;
#pragma unroll
      for (int j = 0; j < 64; ++j) msg[j] = fmaf(av.x, w[j], msg[j]);
#pragma unroll
      for (int j = 0; j < 64; ++j) msg[j] = fmaf(av.y, w[64 + j], msg[j]);
#pragma unroll
      for (int j = 0; j < 64; ++j) msg[j] = fmaf(av.z, w[128 + j], msg[j]);
#pragma unroll
      for (int j = 0; j < 64; ++j) msg[j] = fmaf(av.w, w[192 + j], msg[j]);
    }
    float* xn = xnew + (size_t)c * 64;
#pragma unroll
    for (int j = 0; j < 64; ++j) atomicAdd(xn + j, msg[j]);
  }
}

// ---------------- BN stats: per-channel sum / sumsq over nodes ----------------
__global__ __launch_bounds__(256) void k_bn_stats(
    const float* __restrict__ xnew, float* __restrict__ bnacc, int N) {
  int t = threadIdx.x;
  int ch = t & 63;
  int sl = t >> 6;
  float s = 0.f, s2 = 0.f;
  for (int n = blockIdx.x * 4 + sl; n < N; n += gridDim.x * 4) {
    float v = xnew[(size_t)n * 64 + ch];
    s += v;
    s2 = fmaf(v, v, s2);
  }
  __shared__ float red[256], red2[256];
  red[t] = s;
  red2[t] = s2;
  __syncthreads();
  if (sl == 0) {
    s = red[ch] + red[64 + ch] + red[128 + ch] + red[192 + ch];
    s2 = red2[ch] + red2[64 + ch] + red2[128 + ch] + red2[192 + ch];
    atomicAdd(&bnacc[ch], s);
    atomicAdd(&bnacc[64 + ch], s2);
  }
}

// ---------------- BN apply + softplus + residual ----------------
__global__ __launch_bounds__(256) void k_bn_apply(
    float* __restrict__ x, const float* __restrict__ xnew,
    const float* __restrict__ bnacc, const float* __restrict__ gamma,
    const float* __restrict__ beta, int N) {
  __shared__ float sscale[64], sshift[64];
  if (threadIdx.x < 64) {
    float inv = 1.0f / (float)N;
    float m = bnacc[threadIdx.x] * inv;
    float var = bnacc[64 + threadIdx.x] * inv - m * m;
    float rs = rsqrtf(var + 1e-5f);
    float g = gamma[threadIdx.x];
    sscale[threadIdx.x] = rs * g;
    sshift[threadIdx.x] = beta[threadIdx.x] - m * rs * g;
  }
  __syncthreads();
  size_t total = (size_t)N * 64;
  size_t stride = (size_t)gridDim.x * blockDim.x;
  for (size_t i = (size_t)blockIdx.x * blockDim.x + threadIdx.x; i < total; i += stride) {
    int ch = (int)(i & 63);
    float v = fmaf(xnew[i], sscale[ch], sshift[ch]);
    x[i] += sp_f(v);
  }
}

// ---------------- global mean pool: one block per graph, batch is sorted ----------------
__device__ __forceinline__ int lbound(const int* a, int n, int key) {
  int lo = 0, hi = n;
  while (lo < hi) {
    int mid = (lo + hi) >> 1;
    if (a[mid] < key) lo = mid + 1; else hi = mid;
  }
  return lo;
}

__global__ __launch_bounds__(256) void k_pool(
    const float* __restrict__ x, const int* __restrict__ batch, int N,
    float* __restrict__ g) {
  int b = blockIdx.x;
  int lo = lbound(batch, N, b);
  int hi = lbound(batch, N, b + 1);
  int t = threadIdx.x;
  int ch = t & 63;
  int sl = t >> 6;
  float s = 0.f;
  for (int n = lo + sl; n < hi; n += 4) s += x[(size_t)n * 64 + ch];
  __shared__ float red[4][64];
  red[sl][ch] = s;
  __syncthreads();
  if (t < 64) {
    float tot = red[0][t] + red[1][t] + red[2][t] + red[3][t];
    float cnt = (float)(hi - lo);
    g[(size_t)b * 64 + t] = tot / fmaxf(cnt, 1.0f);
  }
}

// ---------------- predictor MLP: one block (128 thr) per graph ----------------
__global__ __launch_bounds__(128) void k_pred(
    const float* __restrict__ g, const float* __restrict__ pW1,
    const float* __restrict__ pb1, const float* __restrict__ pW2,
    const float* __restrict__ pb2, const float* __restrict__ pW3,
    const float* __restrict__ pb3, float* __restrict__ out) {
  int b = blockIdx.x;
  int t = threadIdx.x;
  __shared__ float sg[64];
  __shared__ float sh1[128];
  __shared__ float red[128];
  if (t < 64) sg[t] = g[(size_t)b * 64 + t];
  __syncthreads();
  float s = pb1[t];
  for (int k = 0; k < 64; ++k) s = fmaf(sg[k], pW1[k * 128 + t], s);
  sh1[t] = sp_f(s);
  __syncthreads();
  s = pb2[t];
  for (int k = 0; k < 128; ++k) s = fmaf(sh1[k], pW2[k * 128 + t], s);
  float h2 = sp_f(s);
  red[t] = h2 * pW3[t];
  __syncthreads();
  for (int off = 64; off > 0; off >>= 1) {
    if (t < off) red[t] += red[t + off];
    __syncthreads();
  }
  if (t == 0) out[b] = red[0] + pb3[0];
}

extern "C" void kernel_launch(void* const* d_in, const int* in_sizes, int n_in,
                              void* d_out, int out_size, void* d_ws, size_t ws_size,
                              hipStream_t stream) {
  const float* x         = (const float*)d_in[0];
  const float* edge_attr = (const float*)d_in[1];
  const float* charge    = (const float*)d_in[2];
  const int*   eidx      = (const int*)d_in[3];
  const int*   batch     = (const int*)d_in[4];
  const float* W_charge  = (const float*)d_in[5];
  const float* b_charge  = (const float*)d_in[6];
  const float* W_atom    = (const float*)d_in[7];
  const float* b_atom    = (const float*)d_in[8];
  const float* W_bond    = (const float*)d_in[9];
  const float* b_bond    = (const float*)d_in[10];
  const float* eW1 = (const float*)d_in[11];
  const float* eb1 = (const float*)d_in[12];
  const float* eW2 = (const float*)d_in[13];
  const float* eb2 = (const float*)d_in[14];
  const float* nW1 = (const float*)d_in[15];
  const float* nb1 = (const float*)d_in[16];
  const float* nW2 = (const float*)d_in[17];
  const float* nb2 = (const float*)d_in[18];
  const float* gam = (const float*)d_in[19];
  const float* bet = (const float*)d_in[20];
  const float* pW1 = (const float*)d_in[21];
  const float* pb1 = (const float*)d_in[22];
  const float* pW2 = (const float*)d_in[23];
  const float* pb2 = (const float*)d_in[24];
  const float* pW3 = (const float*)d_in[25];
  const float* pb3 = (const float*)d_in[26];

  int N = in_sizes[4];
  int E = in_sizes[3] / 2;
  int B = in_sizes[2];
  const int* row = eidx;
  const int* col = eidx + E;

  // workspace carve
  char* w = (char*)d_ws;
  float* xemb = (float*)w; w += (size_t)N * 64 * 4;
  float* ea   = (float*)w; w += (size_t)E * 64 * 4;
  float* up   = (float*)w; w += (size_t)N * 128 * 4;
  float* vbuf = (float*)w; w += (size_t)N * 64 * 4;
  float* xnew = (float*)w; w += (size_t)N * 64 * 4;
  float* gbuf = (float*)w; w += (size_t)B * 64 * 4;
  float* bnacc = (float*)w; w += 128 * 4;

  int nblk = (N + 255) / 256;
  k_embed_nodes<<<nblk, 256, 0, stream>>>(x, batch, charge, W_charge, b_charge,
                                          W_atom, b_atom, xemb, N);
  k_embed_bonds<<<4096, 256, 0, stream>>>(edge_attr, W_bond, b_bond, ea, E);

  for (int i = 0; i < 3; ++i) {
    const float* leW1 = eW1 + (size_t)i * 192 * 64;
    const float* leb1 = eb1 + (size_t)i * 64;
    const float* leW2 = eW2 + (size_t)i * 64 * 64;
    const float* leb2 = eb2 + (size_t)i * 64;
    const float* lnW1 = nW1 + (size_t)i * 128 * 64;
    const float* lnb1 = nb1 + (size_t)i * 64;
    const float* lnW2 = nW2 + (size_t)i * 64 * 64;
    const float* lnb2 = nb2 + (size_t)i * 64;

    k_node_pre<<<nblk, 256, 0, stream>>>(xemb, leW1, lnW1, up, vbuf, N);
    hipMemsetAsync(xnew, 0, (size_t)N * 64 * 4, stream);
    hipMemsetAsync(bnacc, 0, 128 * 4, stream);
    k_edge<<<2048, 256, 0, stream>>>(row, col, up, vbuf, ea,
                                     leW1 + 128 * 64, leb1, leW2, leb2,
                                     lnW1 + 64 * 64, lnb1, lnW2, lnb2, xnew, E);
    k_bn_stats<<<1024, 256, 0, stream>>>(xnew, bnacc, N);
    k_bn_apply<<<4096, 256, 0, stream>>>(xemb, xnew, bnacc, gam + (size_t)i * 64,
                                         bet + (size_t)i * 64, N);
  }

  k_pool<<<B, 256, 0, stream>>>(xemb, batch, N, gbuf);
  k_pred<<<B, 128, 0, stream>>>(gbuf, pW1, pb1, pW2, pb2, pW3, pb3, (float*)d_out);
}

// Round 2
// 5563.822 us; speedup vs baseline: 3.5920x; 3.5920x over previous
//
#include <hip/hip_runtime.h>
#include <math.h>

typedef short v8s __attribute__((ext_vector_type(8)));   // 8 bf16
typedef float v4f __attribute__((ext_vector_type(4)));

__device__ __forceinline__ float sp_f(float x) {
  return fmaxf(x, 0.0f) + log1pf(__expf(-fabsf(x)));
}

__device__ __forceinline__ unsigned short f2bf(float f) {
  union { float f; unsigned u; } x; x.f = f;
  unsigned r = (x.u + 0x7FFF + ((x.u >> 16) & 1)) >> 16;
  return (unsigned short)r;
}

// ---------------- node embedding (fp32, unchanged) ----------------
__global__ __launch_bounds__(256) void k_embed_nodes(
    const float* __restrict__ x, const int* __restrict__ batch,
    const float* __restrict__ charge, const float* __restrict__ W_charge,
    const float* __restrict__ b_charge, const float* __restrict__ W_atom,
    const float* __restrict__ b_atom, float* __restrict__ xemb, int N) {
  __shared__ float sW[108 * 64];
  __shared__ float sb[64];
  __shared__ float sWc[16];
  __shared__ float sbc[16];
  for (int i = threadIdx.x; i < 108 * 64; i += blockDim.x) sW[i] = W_atom[i];
  if (threadIdx.x < 64) sb[threadIdx.x] = b_atom[threadIdx.x];
  if (threadIdx.x < 16) {
    sWc[threadIdx.x] = W_charge[threadIdx.x];
    sbc[threadIdx.x] = b_charge[threadIdx.x];
  }
  __syncthreads();
  int stride = gridDim.x * blockDim.x;
  for (int n = blockIdx.x * blockDim.x + threadIdx.x; n < N; n += stride) {
    float acc[64];
#pragma unroll
    for (int j = 0; j < 64; ++j) acc[j] = sb[j];
    const float* xr = x + (size_t)n * 92;
    for (int k = 0; k < 92; ++k) {
      float a = xr[k];
      const float* w = sW + k * 64;
#pragma unroll
      for (int j = 0; j < 64; ++j) acc[j] = fmaf(a, w[j], acc[j]);
    }
    float ch = charge[batch[n]];
#pragma unroll
    for (int c = 0; c < 16; ++c) {
      float cf = fmaf(ch, sWc[c], sbc[c]);
      const float* w = sW + (92 + c) * 64;
#pragma unroll
      for (int j = 0; j < 64; ++j) acc[j] = fmaf(cf, w[j], acc[j]);
    }
    float* o = xemb + (size_t)n * 64;
#pragma unroll
    for (int q = 0; q < 16; ++q)
      ((float4*)o)[q] = make_float4(acc[4*q], acc[4*q+1], acc[4*q+2], acc[4*q+3]);
  }
}

// ---------------- CSR build: hist / scan / scatter ----------------
__global__ __launch_bounds__(256) void k_hist(const int* __restrict__ col,
                                              int* __restrict__ counts, int E) {
  int stride = gridDim.x * blockDim.x;
  for (int e = blockIdx.x * blockDim.x + threadIdx.x; e < E; e += stride)
    atomicAdd(&counts[col[e]], 1);
}

__global__ __launch_bounds__(256) void k_scan1(const int* __restrict__ counts,
                                               int* __restrict__ scan_tmp,
                                               int* __restrict__ bsum, int N) {
  __shared__ int sd[2][256];
  int t = threadIdx.x;
  int i = blockIdx.x * 256 + t;
  int v = (i < N) ? counts[i] : 0;
  sd[0][t] = v;
  __syncthreads();
  int s = 0;
#pragma unroll
  for (int off = 1; off < 256; off <<= 1) {
    int nv = sd[s][t];
    if (t >= off) nv += sd[s][t - off];
    sd[s ^ 1][t] = nv;
    s ^= 1;
    __syncthreads();
  }
  if (i < N) scan_tmp[i] = sd[s][t];
  if (t == 255) bsum[blockIdx.x] = sd[s][255];
}

__global__ __launch_bounds__(256) void k_scan2(int* __restrict__ b, int NB) {
  __shared__ int sd[2][256];
  __shared__ int carry_s;
  int t = threadIdx.x;
  if (t == 0) carry_s = 0;
  __syncthreads();
  for (int base = 0; base < NB; base += 256) {
    int i = base + t;
    int v = (i < NB) ? b[i] : 0;
    sd[0][t] = v;
    __syncthreads();
    int s = 0;
#pragma unroll
    for (int off = 1; off < 256; off <<= 1) {
      int nv = sd[s][t];
      if (t >= off) nv += sd[s][t - off];
      sd[s ^ 1][t] = nv;
      s ^= 1;
      __syncthreads();
    }
    int c = carry_s;
    int tot = sd[s][255];
    if (i < NB) b[i] = sd[s][t] + c;
    __syncthreads();
    if (t == 0) carry_s = c + tot;
    __syncthreads();
  }
}

__global__ __launch_bounds__(256) void k_scan3(const int* __restrict__ counts,
                                               const int* __restrict__ scan_tmp,
                                               const int* __restrict__ bsum,
                                               int* __restrict__ cursor, int N) {
  int i = blockIdx.x * 256 + threadIdx.x;
  if (i < N) {
    int base = (blockIdx.x > 0) ? bsum[blockIdx.x - 1] : 0;
    cursor[i] = scan_tmp[i] - counts[i] + base;
  }
}

__global__ __launch_bounds__(256) void k_scatter(
    const int* __restrict__ row, const int* __restrict__ col,
    int* __restrict__ cursor, int* __restrict__ perm,
    int* __restrict__ row_s, int* __restrict__ col_s, int E) {
  int stride = gridDim.x * blockDim.x;
  for (int e = blockIdx.x * blockDim.x + threadIdx.x; e < E; e += stride) {
    int c = col[e];
    int p = atomicAdd(&cursor[c], 1);
    perm[p] = e;
    row_s[p] = row[e];
    col_s[p] = c;
  }
}

// ---------------- bond embedding into sorted order, bf16 out ----------------
__global__ __launch_bounds__(256) void k_embed_bonds_perm(
    const float* __restrict__ eattr, const int* __restrict__ perm,
    const float* __restrict__ W_bond, const float* __restrict__ b_bond,
    unsigned short* __restrict__ ea16, int E) {
  __shared__ float sW[41 * 64];
  __shared__ float sb[64];
  for (int i = threadIdx.x; i < 41 * 64; i += blockDim.x) sW[i] = W_bond[i];
  if (threadIdx.x < 64) sb[threadIdx.x] = b_bond[threadIdx.x];
  __syncthreads();
  int stride = gridDim.x * blockDim.x;
  for (int s = blockIdx.x * blockDim.x + threadIdx.x; s < E; s += stride) {
    int e = perm[s];
    float acc[64];
#pragma unroll
    for (int j = 0; j < 64; ++j) acc[j] = sb[j];
    const float* er = eattr + (size_t)e * 41;
    for (int k = 0; k < 41; ++k) {
      float a = er[k];
      const float* w = sW + k * 64;
#pragma unroll
      for (int j = 0; j < 64; ++j) acc[j] = fmaf(a, w[j], acc[j]);
    }
#pragma unroll
    for (int q8 = 0; q8 < 8; ++q8) {
      unsigned short tmp[8];
#pragma unroll
      for (int j = 0; j < 8; ++j) tmp[j] = f2bf(acc[q8 * 8 + j]);
      *(uint4*)&ea16[(size_t)s * 64 + q8 * 8] = *(uint4*)tmp;
    }
  }
}

// ---------------- per-layer node-side precompute (fp32, unchanged) ----------------
__global__ __launch_bounds__(256) void k_node_pre(
    const float* __restrict__ xemb, const float* __restrict__ eW1,
    const float* __restrict__ nW1, float* __restrict__ up,
    float* __restrict__ vbuf, int N) {
  __shared__ float sWa[64 * 64];
  __shared__ float sWb[64 * 64];
  __shared__ float sWp[64 * 64];
  for (int i = threadIdx.x; i < 64 * 64; i += blockDim.x) {
    sWa[i] = eW1[i];
    sWb[i] = eW1[64 * 64 + i];
    sWp[i] = nW1[i];
  }
  __syncthreads();
  int stride = gridDim.x * blockDim.x;
  for (int n = blockIdx.x * blockDim.x + threadIdx.x; n < N; n += stride) {
    const float4* xr4 = (const float4*)(xemb + (size_t)n * 64);
    float u[64], p[64];
#pragma unroll
    for (int j = 0; j < 64; ++j) { u[j] = 0.f; p[j] = 0.f; }
    for (int k4 = 0; k4 < 16; ++k4) {
      float4 av = xr4[k4];
      const float* wa = sWa + k4 * 256;
      const float* wp = sWp + k4 * 256;
#pragma unroll
      for (int j = 0; j < 64; ++j) u[j] = fmaf(av.x, wa[j], u[j]);
#pragma unroll
      for (int j = 0; j < 64; ++j) p[j] = fmaf(av.x, wp[j], p[j]);
#pragma unroll
      for (int j = 0; j < 64; ++j) u[j] = fmaf(av.y, wa[64 + j], u[j]);
#pragma unroll
      for (int j = 0; j < 64; ++j) p[j] = fmaf(av.y, wp[64 + j], p[j]);
#pragma unroll
      for (int j = 0; j < 64; ++j) u[j] = fmaf(av.z, wa[128 + j], u[j]);
#pragma unroll
      for (int j = 0; j < 64; ++j) p[j] = fmaf(av.z, wp[128 + j], p[j]);
#pragma unroll
      for (int j = 0; j < 64; ++j) u[j] = fmaf(av.w, wa[192 + j], u[j]);
#pragma unroll
      for (int j = 0; j < 64; ++j) p[j] = fmaf(av.w, wp[192 + j], p[j]);
    }
    float* o = up + (size_t)n * 128;
#pragma unroll
    for (int q = 0; q < 16; ++q)
      ((float4*)o)[q] = make_float4(u[4*q], u[4*q+1], u[4*q+2], u[4*q+3]);
#pragma unroll
    for (int q = 0; q < 16; ++q)
      ((float4*)(o + 64))[q] = make_float4(p[4*q], p[4*q+1], p[4*q+2], p[4*q+3]);
    float vv[64];
#pragma unroll
    for (int j = 0; j < 64; ++j) vv[j] = 0.f;
    for (int k4 = 0; k4 < 16; ++k4) {
      float4 av = xr4[k4];
      const float* wb = sWb + k4 * 256;
#pragma unroll
      for (int j = 0; j < 64; ++j) vv[j] = fmaf(av.x, wb[j], vv[j]);
#pragma unroll
      for (int j = 0; j < 64; ++j) vv[j] = fmaf(av.y, wb[64 + j], vv[j]);
#pragma unroll
      for (int j = 0; j < 64; ++j) vv[j] = fmaf(av.z, wb[128 + j], vv[j]);
#pragma unroll
      for (int j = 0; j < 64; ++j) vv[j] = fmaf(av.w, wb[192 + j], vv[j]);
    }
    float* ov = vbuf + (size_t)n * 64;
#pragma unroll
    for (int q = 0; q < 16; ++q)
      ((float4*)ov)[q] = make_float4(vv[4*q], vv[4*q+1], vv[4*q+2], vv[4*q+3]);
  }
}

// ---------------- fused per-layer edge kernel, MFMA bf16 ----------------
// tile = 128 edges (sorted by col), 4 waves; wave w owns rows [w*32, w*32+32)
#define READ_FRAGS(P)                                                        \
  {                                                                          \
    const v8s* wp_ = (const v8s*)(sWf + (P) * 4096);                         \
    _Pragma("unroll") for (int ct = 0; ct < 4; ++ct)                         \
        _Pragma("unroll") for (int kh = 0; kh < 2; ++kh)                     \
            bfr[ct][kh] = wp_[(ct * 2 + kh) * 64 + l];                       \
    _Pragma("unroll") for (int rb = 0; rb < 2; ++rb)                         \
        _Pragma("unroll") for (int kh = 0; kh < 2; ++kh) {                   \
      int row_ = rbase + rb * 16 + c16;                                      \
      af[rb][kh] = *(const v8s*)&sA[row_ * 64 +                              \
                                    ((kh * 32 + q * 8) ^ ((row_ & 7) << 3))];\
    }                                                                        \
  }

#define DO_MFMA()                                                            \
  _Pragma("unroll") for (int rb = 0; rb < 2; ++rb)                           \
      _Pragma("unroll") for (int ct = 0; ct < 4; ++ct) {                     \
    v4f a_ = {0.f, 0.f, 0.f, 0.f};                                           \
    a_ = __builtin_amdgcn_mfma_f32_16x16x32_bf16(af[rb][0], bfr[ct][0], a_,  \
                                                 0, 0, 0);                   \
    a_ = __builtin_amdgcn_mfma_f32_16x16x32_bf16(af[rb][1], bfr[ct][1], a_,  \
                                                 0, 0, 0);                   \
    acc[rb][ct] = a_;                                                        \
  }

__global__ __launch_bounds__(256, 3) void k_edge_mfma(
    const int* __restrict__ row_s, const int* __restrict__ col_s,
    unsigned short* __restrict__ ea16, const float* __restrict__ up,
    const float* __restrict__ vbuf, const float* __restrict__ W1c,
    const float* __restrict__ eb1, const float* __restrict__ eW2,
    const float* __restrict__ eb2, const float* __restrict__ nW1b,
    const float* __restrict__ nb1, const float* __restrict__ nW2,
    const float* __restrict__ nb2, float* __restrict__ xnew, int E) {
  __shared__ unsigned short sWf[4 * 4096];  // fragment-layout weights, bf16
  __shared__ unsigned short sA[128 * 64];   // activation tile, swizzled
  __shared__ float sB[4][64];

  int tid = threadIdx.x;
  int te = blockIdx.x * 128;

  // stage weights into B-fragment layout: frag[(ct*2+kh)*512 + lane*8 + j]
  // = W[kh*32 + (lane>>4)*8 + j][ct*16 + (lane&15)]
  for (int f = tid; f < 4096; f += 256) {
    int j = f & 7, ln = (f >> 3) & 63, kh = (f >> 9) & 1, ct = f >> 10;
    int k = kh * 32 + (ln >> 4) * 8 + j;
    int n = ct * 16 + (ln & 15);
    int wi = k * 64 + n;
    sWf[f] = f2bf(W1c[wi]);
    sWf[4096 + f] = f2bf(eW2[wi]);
    sWf[8192 + f] = f2bf(nW1b[wi]);
    sWf[12288 + f] = f2bf(nW2[wi]);
  }
  if (tid < 64) {
    sB[0][tid] = eb1[tid];
    sB[1][tid] = eb2[tid];
    sB[2][tid] = nb1[tid];
    sB[3][tid] = nb2[tid];
  }
  // stage A tile (ea, bf16) swizzled: ushort idx = row*64 + (col ^ ((row&7)<<3))
  for (int i = tid; i < 1024; i += 256) {
    int r = i >> 3, cc = i & 7;
    int e = te + r;
    if (e >= E) e = E - 1;
    uint4 d = *(const uint4*)&ea16[(size_t)e * 64 + cc * 8];
    *(uint4*)&sA[r * 64 + ((cc * 8) ^ ((r & 7) << 3))] = d;
  }

  int w = tid >> 6, l = tid & 63, q = l >> 4, c16 = l & 15;
  int rbase = w * 32;

  int rid[2][4], cid[2][4], eid[2][4];
#pragma unroll
  for (int rb = 0; rb < 2; ++rb)
#pragma unroll
    for (int r = 0; r < 4; ++r) {
      int rit = rbase + rb * 16 + q * 4 + r;
      int e = te + rit;
      eid[rb][r] = e;
      int ec = e < E ? e : E - 1;
      rid[rb][r] = row_s[ec];
      cid[rb][r] = col_s[ec];
    }

  v8s af[2][2];
  v8s bfr[4][2];
  v4f acc[2][4];

  // ---- phase 0: T = sp(ea@W1c + b1 + u[row] + v[col]) ----
  __syncthreads();
  READ_FRAGS(0);
  __syncthreads();
  DO_MFMA();
#pragma unroll
  for (int rb = 0; rb < 2; ++rb)
#pragma unroll
    for (int ct = 0; ct < 4; ++ct) {
      int n = ct * 16 + c16;
#pragma unroll
      for (int r = 0; r < 4; ++r) {
        float t = acc[rb][ct][r] + sB[0][n] +
                  up[(size_t)rid[rb][r] * 128 + n] +
                  vbuf[(size_t)cid[rb][r] * 64 + n];
        t = sp_f(t);
        int row = rbase + rb * 16 + q * 4 + r;
        sA[row * 64 + (n ^ ((row & 7) << 3))] = f2bf(t);
      }
    }

  // ---- phase 1: ea' = T@eW2 + b2 (store global bf16 + LDS) ----
  __syncthreads();
  READ_FRAGS(1);
  __syncthreads();
  DO_MFMA();
#pragma unroll
  for (int rb = 0; rb < 2; ++rb)
#pragma unroll
    for (int ct = 0; ct < 4; ++ct) {
      int n = ct * 16 + c16;
#pragma unroll
      for (int r = 0; r < 4; ++r) {
        float en = acc[rb][ct][r] + sB[1][n];
        unsigned short h = f2bf(en);
        int row = rbase + rb * 16 + q * 4 + r;
        sA[row * 64 + (n ^ ((row & 7) << 3))] = h;
        if (eid[rb][r] < E) ea16[(size_t)eid[rb][r] * 64 + n] = h;
      }
    }

  // ---- phase 2: T2 = sp(ea'@nW1b + b3 + p[row]) ----
  __syncthreads();
  READ_FRAGS(2);
  __syncthreads();
  DO_MFMA();
#pragma unroll
  for (int rb = 0; rb < 2; ++rb)
#pragma unroll
    for (int ct = 0; ct < 4; ++ct) {
      int n = ct * 16 + c16;
#pragma unroll
      for (int r = 0; r < 4; ++r) {
        float t2 = acc[rb][ct][r] + sB[2][n] +
                   up[(size_t)rid[rb][r] * 128 + 64 + n];
        t2 = sp_f(t2);
        int row = rbase + rb * 16 + q * 4 + r;
        sA[row * 64 + (n ^ ((row & 7) << 3))] = f2bf(t2);
      }
    }

  // ---- phase 3: msg = T2@nW2 + b4 ; scatter ----
  __syncthreads();
  READ_FRAGS(3);
  __syncthreads();
  DO_MFMA();
#pragma unroll
  for (int rb = 0; rb < 2; ++rb)
#pragma unroll
    for (int ct = 0; ct < 4; ++ct) {
      int n = ct * 16 + c16;
#pragma unroll
      for (int r = 0; r < 4; ++r) {
        float msg = acc[rb][ct][r] + sB[3][n];
        if (eid[rb][r] < E)
          atomicAdd(&xnew[(size_t)cid[rb][r] * 64 + n], msg);
      }
    }
}

// ---------------- BN stats ----------------
__global__ __launch_bounds__(256) void k_bn_stats(
    const float* __restrict__ xnew, float* __restrict__ bnacc, int N) {
  int t = threadIdx.x;
  int ch = t & 63;
  int sl = t >> 6;
  float s = 0.f, s2 = 0.f;
  for (int n = blockIdx.x * 4 + sl; n < N; n += gridDim.x * 4) {
    float v = xnew[(size_t)n * 64 + ch];
    s += v;
    s2 = fmaf(v, v, s2);
  }
  __shared__ float red[256], red2[256];
  red[t] = s;
  red2[t] = s2;
  __syncthreads();
  if (sl == 0) {
    s = red[ch] + red[64 + ch] + red[128 + ch] + red[192 + ch];
    s2 = red2[ch] + red2[64 + ch] + red2[128 + ch] + red2[192 + ch];
    atomicAdd(&bnacc[ch], s);
    atomicAdd(&bnacc[64 + ch], s2);
  }
}

// ---------------- BN apply + softplus + residual ----------------
__global__ __launch_bounds__(256) void k_bn_apply(
    float* __restrict__ x, const float* __restrict__ xnew,
    const float* __restrict__ bnacc, const float* __restrict__ gamma,
    const float* __restrict__ beta, int N) {
  __shared__ float sscale[64], sshift[64];
  if (threadIdx.x < 64) {
    float inv = 1.0f / (float)N;
    float m = bnacc[threadIdx.x] * inv;
    float var = bnacc[64 + threadIdx.x] * inv - m * m;
    float rs = rsqrtf(var + 1e-5f);
    float g = gamma[threadIdx.x];
    sscale[threadIdx.x] = rs * g;
    sshift[threadIdx.x] = beta[threadIdx.x] - m * rs * g;
  }
  __syncthreads();
  size_t total = (size_t)N * 64;
  size_t stride = (size_t)gridDim.x * blockDim.x;
  for (size_t i = (size_t)blockIdx.x * blockDim.x + threadIdx.x; i < total; i += stride) {
    int ch = (int)(i & 63);
    float v = fmaf(xnew[i], sscale[ch], sshift[ch]);
    x[i] += sp_f(v);
  }
}

// ---------------- pool + predictor (unchanged) ----------------
__device__ __forceinline__ int lbound(const int* a, int n, int key) {
  int lo = 0, hi = n;
  while (lo < hi) {
    int mid = (lo + hi) >> 1;
    if (a[mid] < key) lo = mid + 1; else hi = mid;
  }
  return lo;
}

__global__ __launch_bounds__(256) void k_pool(
    const float* __restrict__ x, const int* __restrict__ batch, int N,
    float* __restrict__ g) {
  int b = blockIdx.x;
  int lo = lbound(batch, N, b);
  int hi = lbound(batch, N, b + 1);
  int t = threadIdx.x;
  int ch = t & 63;
  int sl = t >> 6;
  float s = 0.f;
  for (int n = lo + sl; n < hi; n += 4) s += x[(size_t)n * 64 + ch];
  __shared__ float red[4][64];
  red[sl][ch] = s;
  __syncthreads();
  if (t < 64) {
    float tot = red[0][t] + red[1][t] + red[2][t] + red[3][t];
    float cnt = (float)(hi - lo);
    g[(size_t)b * 64 + t] = tot / fmaxf(cnt, 1.0f);
  }
}

__global__ __launch_bounds__(128) void k_pred(
    const float* __restrict__ g, const float* __restrict__ pW1,
    const float* __restrict__ pb1, const float* __restrict__ pW2,
    const float* __restrict__ pb2, const float* __restrict__ pW3,
    const float* __restrict__ pb3, float* __restrict__ out) {
  int b = blockIdx.x;
  int t = threadIdx.x;
  __shared__ float sg[64];
  __shared__ float sh1[128];
  __shared__ float red[128];
  if (t < 64) sg[t] = g[(size_t)b * 64 + t];
  __syncthreads();
  float s = pb1[t];
  for (int k = 0; k < 64; ++k) s = fmaf(sg[k], pW1[k * 128 + t], s);
  sh1[t] = sp_f(s);
  __syncthreads();
  s = pb2[t];
  for (int k = 0; k < 128; ++k) s = fmaf(sh1[k], pW2[k * 128 + t], s);
  float h2 = sp_f(s);
  red[t] = h2 * pW3[t];
  __syncthreads();
  for (int off = 64; off > 0; off >>= 1) {
    if (t < off) red[t] += red[t + off];
    __syncthreads();
  }
  if (t == 0) out[b] = red[0] + pb3[0];
}

extern "C" void kernel_launch(void* const* d_in, const int* in_sizes, int n_in,
                              void* d_out, int out_size, void* d_ws, size_t ws_size,
                              hipStream_t stream) {
  const float* x         = (const float*)d_in[0];
  const float* edge_attr = (const float*)d_in[1];
  const float* charge    = (const float*)d_in[2];
  const int*   eidx      = (const int*)d_in[3];
  const int*   batch     = (const int*)d_in[4];
  const float* W_charge  = (const float*)d_in[5];
  const float* b_charge  = (const float*)d_in[6];
  const float* W_atom    = (const float*)d_in[7];
  const float* b_atom    = (const float*)d_in[8];
  const float* W_bond    = (const float*)d_in[9];
  const float* b_bond    = (const float*)d_in[10];
  const float* eW1 = (const float*)d_in[11];
  const float* eb1 = (const float*)d_in[12];
  const float* eW2 = (const float*)d_in[13];
  const float* eb2 = (const float*)d_in[14];
  const float* nW1 = (const float*)d_in[15];
  const float* nb1 = (const float*)d_in[16];
  const float* nW2 = (const float*)d_in[17];
  const float* nb2 = (const float*)d_in[18];
  const float* gam = (const float*)d_in[19];
  const float* bet = (const float*)d_in[20];
  const float* pW1 = (const float*)d_in[21];
  const float* pb1 = (const float*)d_in[22];
  const float* pW2 = (const float*)d_in[23];
  const float* pb2 = (const float*)d_in[24];
  const float* pW3 = (const float*)d_in[25];
  const float* pb3 = (const float*)d_in[26];

  int N = in_sizes[4];
  int E = in_sizes[3] / 2;
  int B = in_sizes[2];
  const int* row = eidx;
  const int* col = eidx + E;

  // workspace carve (aligned chunks)
  char* wptr = (char*)d_ws;
  unsigned short* ea16 = (unsigned short*)wptr; wptr += (((size_t)E * 64 * 2 + 255) & ~255ull);
  float* xemb = (float*)wptr; wptr += (size_t)N * 64 * 4;
  float* up   = (float*)wptr; wptr += (size_t)N * 128 * 4;
  float* vbuf = (float*)wptr; wptr += (size_t)N * 64 * 4;
  float* xnew = (float*)wptr; wptr += (size_t)N * 64 * 4;
  float* gbuf = (float*)wptr; wptr += (size_t)B * 64 * 4;
  float* bnacc = (float*)wptr; wptr += 256 * 4;
  int* counts = (int*)wptr;   wptr += (size_t)N * 4;
  int* scan_tmp = (int*)wptr; wptr += (size_t)N * 4;
  int* cursor = (int*)wptr;   wptr += (size_t)N * 4;
  int* bsum = (int*)wptr;     wptr += 4096;
  int* perm = (int*)wptr;     wptr += (size_t)E * 4;
  int* row_s = (int*)wptr;    wptr += (size_t)E * 4;
  int* col_s = (int*)wptr;    wptr += (size_t)E * 4;

  int NB = (N + 255) / 256;

  // CSR sort of edges by col
  hipMemsetAsync(counts, 0, (size_t)N * 4, stream);
  k_hist<<<2048, 256, 0, stream>>>(col, counts, E);
  k_scan1<<<NB, 256, 0, stream>>>(counts, scan_tmp, bsum, N);
  k_scan2<<<1, 256, 0, stream>>>(bsum, NB);
  k_scan3<<<NB, 256, 0, stream>>>(counts, scan_tmp, bsum, cursor, N);
  k_scatter<<<2048, 256, 0, stream>>>(row, col, cursor, perm, row_s, col_s, E);

  k_embed_nodes<<<NB, 256, 0, stream>>>(x, batch, charge, W_charge, b_charge,
                                        W_atom, b_atom, xemb, N);
  k_embed_bonds_perm<<<4096, 256, 0, stream>>>(edge_attr, perm, W_bond, b_bond,
                                               ea16, E);

  int gridE = (E + 127) / 128;
  for (int i = 0; i < 3; ++i) {
    const float* leW1 = eW1 + (size_t)i * 192 * 64;
    const float* leb1 = eb1 + (size_t)i * 64;
    const float* leW2 = eW2 + (size_t)i * 64 * 64;
    const float* leb2 = eb2 + (size_t)i * 64;
    const float* lnW1 = nW1 + (size_t)i * 128 * 64;
    const float* lnb1 = nb1 + (size_t)i * 64;
    const float* lnW2 = nW2 + (size_t)i * 64 * 64;
    const float* lnb2 = nb2 + (size_t)i * 64;

    k_node_pre<<<NB, 256, 0, stream>>>(xemb, leW1, lnW1, up, vbuf, N);
    hipMemsetAsync(xnew, 0, (size_t)N * 64 * 4, stream);
    hipMemsetAsync(bnacc, 0, 256 * 4, stream);
    k_edge_mfma<<<gridE, 256, 0, stream>>>(row_s, col_s, ea16, up, vbuf,
                                           leW1 + 128 * 64, leb1, leW2, leb2,
                                           lnW1 + 64 * 64, lnb1, lnW2, lnb2,
                                           xnew, E);
    k_bn_stats<<<1024, 256, 0, stream>>>(xnew, bnacc, N);
    k_bn_apply<<<4096, 256, 0, stream>>>(xemb, xnew, bnacc, gam + (size_t)i * 64,
                                         bet + (size_t)i * 64, N);
  }

  k_pool<<<B, 256, 0, stream>>>(xemb, batch, N, gbuf);
  k_pred<<<B, 128, 0, stream>>>(gbuf, pW1, pb1, pW2, pb2, pW3, pb3, (float*)d_out);
}

// Round 3
// 2693.686 us; speedup vs baseline: 7.4193x; 2.0655x over previous
//
#include <hip/hip_runtime.h>
#include <math.h>

typedef short v8s __attribute__((ext_vector_type(8)));   // 8 bf16
typedef float v4f __attribute__((ext_vector_type(4)));

// fast softplus: max(x,0) + ln2*log2(1+exp(-|x|)); HW exp/log, ~3e-5 abs err
__device__ __forceinline__ float sp_f(float x) {
  return fmaxf(x, 0.0f) + 0.69314718056f * __log2f(1.0f + __expf(-fabsf(x)));
}

__device__ __forceinline__ unsigned short f2bf(float f) {
  union { float f; unsigned u; } x; x.f = f;
  unsigned r = (x.u + 0x7FFF + ((x.u >> 16) & 1)) >> 16;
  return (unsigned short)r;
}

__device__ __forceinline__ float bf2f(unsigned short h) {
  union { unsigned u; float f; } x; x.u = ((unsigned)h) << 16;
  return x.f;
}

// ---------------- node embedding (fp32) ----------------
__global__ __launch_bounds__(256) void k_embed_nodes(
    const float* __restrict__ x, const int* __restrict__ batch,
    const float* __restrict__ charge, const float* __restrict__ W_charge,
    const float* __restrict__ b_charge, const float* __restrict__ W_atom,
    const float* __restrict__ b_atom, float* __restrict__ xemb, int N) {
  __shared__ float sW[108 * 64];
  __shared__ float sb[64];
  __shared__ float sWc[16];
  __shared__ float sbc[16];
  for (int i = threadIdx.x; i < 108 * 64; i += blockDim.x) sW[i] = W_atom[i];
  if (threadIdx.x < 64) sb[threadIdx.x] = b_atom[threadIdx.x];
  if (threadIdx.x < 16) {
    sWc[threadIdx.x] = W_charge[threadIdx.x];
    sbc[threadIdx.x] = b_charge[threadIdx.x];
  }
  __syncthreads();
  int stride = gridDim.x * blockDim.x;
  for (int n = blockIdx.x * blockDim.x + threadIdx.x; n < N; n += stride) {
    float acc[64];
#pragma unroll
    for (int j = 0; j < 64; ++j) acc[j] = sb[j];
    const float* xr = x + (size_t)n * 92;
    for (int k = 0; k < 92; ++k) {
      float a = xr[k];
      const float* w = sW + k * 64;
#pragma unroll
      for (int j = 0; j < 64; ++j) acc[j] = fmaf(a, w[j], acc[j]);
    }
    float ch = charge[batch[n]];
#pragma unroll
    for (int c = 0; c < 16; ++c) {
      float cf = fmaf(ch, sWc[c], sbc[c]);
      const float* w = sW + (92 + c) * 64;
#pragma unroll
      for (int j = 0; j < 64; ++j) acc[j] = fmaf(cf, w[j], acc[j]);
    }
    float* o = xemb + (size_t)n * 64;
#pragma unroll
    for (int q = 0; q < 16; ++q)
      ((float4*)o)[q] = make_float4(acc[4*q], acc[4*q+1], acc[4*q+2], acc[4*q+3]);
  }
}

// ---------------- CSR build ----------------
__global__ __launch_bounds__(256) void k_hist(const int* __restrict__ col,
                                              int* __restrict__ counts, int E) {
  int stride = gridDim.x * blockDim.x;
  for (int e = blockIdx.x * blockDim.x + threadIdx.x; e < E; e += stride)
    atomicAdd(&counts[col[e]], 1);
}

__global__ __launch_bounds__(256) void k_scan1(const int* __restrict__ counts,
                                               int* __restrict__ scan_tmp,
                                               int* __restrict__ bsum, int N) {
  __shared__ int sd[2][256];
  int t = threadIdx.x;
  int i = blockIdx.x * 256 + t;
  int v = (i < N) ? counts[i] : 0;
  sd[0][t] = v;
  __syncthreads();
  int s = 0;
#pragma unroll
  for (int off = 1; off < 256; off <<= 1) {
    int nv = sd[s][t];
    if (t >= off) nv += sd[s][t - off];
    sd[s ^ 1][t] = nv;
    s ^= 1;
    __syncthreads();
  }
  if (i < N) scan_tmp[i] = sd[s][t];
  if (t == 255) bsum[blockIdx.x] = sd[s][255];
}

__global__ __launch_bounds__(256) void k_scan2(int* __restrict__ b, int NB) {
  __shared__ int sd[2][256];
  __shared__ int carry_s;
  int t = threadIdx.x;
  if (t == 0) carry_s = 0;
  __syncthreads();
  for (int base = 0; base < NB; base += 256) {
    int i = base + t;
    int v = (i < NB) ? b[i] : 0;
    sd[0][t] = v;
    __syncthreads();
    int s = 0;
#pragma unroll
    for (int off = 1; off < 256; off <<= 1) {
      int nv = sd[s][t];
      if (t >= off) nv += sd[s][t - off];
      sd[s ^ 1][t] = nv;
      s ^= 1;
      __syncthreads();
    }
    int c = carry_s;
    int tot = sd[s][255];
    if (i < NB) b[i] = sd[s][t] + c;
    __syncthreads();
    if (t == 0) carry_s = c + tot;
    __syncthreads();
  }
}

__global__ __launch_bounds__(256) void k_scan3(const int* __restrict__ counts,
                                               const int* __restrict__ scan_tmp,
                                               const int* __restrict__ bsum,
                                               int* __restrict__ cursor, int N) {
  int i = blockIdx.x * 256 + threadIdx.x;
  if (i < N) {
    int base = (blockIdx.x > 0) ? bsum[blockIdx.x - 1] : 0;
    cursor[i] = scan_tmp[i] - counts[i] + base;
  }
}

__global__ __launch_bounds__(256) void k_scatter(
    const int* __restrict__ row, const int* __restrict__ col,
    int* __restrict__ cursor, int* __restrict__ perm,
    int* __restrict__ row_s, int* __restrict__ col_s, int E) {
  int stride = gridDim.x * blockDim.x;
  for (int e = blockIdx.x * blockDim.x + threadIdx.x; e < E; e += stride) {
    int c = col[e];
    int p = atomicAdd(&cursor[c], 1);
    perm[p] = e;
    row_s[p] = row[e];
    col_s[p] = c;
  }
}

// ---------------- bond embedding into sorted order, bf16 out ----------------
__global__ __launch_bounds__(256) void k_embed_bonds_perm(
    const float* __restrict__ eattr, const int* __restrict__ perm,
    const float* __restrict__ W_bond, const float* __restrict__ b_bond,
    unsigned short* __restrict__ ea16, int E) {
  __shared__ float sW[41 * 64];
  __shared__ float sb[64];
  for (int i = threadIdx.x; i < 41 * 64; i += blockDim.x) sW[i] = W_bond[i];
  if (threadIdx.x < 64) sb[threadIdx.x] = b_bond[threadIdx.x];
  __syncthreads();
  int stride = gridDim.x * blockDim.x;
  for (int s = blockIdx.x * blockDim.x + threadIdx.x; s < E; s += stride) {
    int e = perm[s];
    float acc[64];
#pragma unroll
    for (int j = 0; j < 64; ++j) acc[j] = sb[j];
    const float* er = eattr + (size_t)e * 41;
    for (int k = 0; k < 41; ++k) {
      float a = er[k];
      const float* w = sW + k * 64;
#pragma unroll
      for (int j = 0; j < 64; ++j) acc[j] = fmaf(a, w[j], acc[j]);
    }
#pragma unroll
    for (int q8 = 0; q8 < 8; ++q8) {
      unsigned short tmp[8];
#pragma unroll
      for (int j = 0; j < 8; ++j) tmp[j] = f2bf(acc[q8 * 8 + j]);
      *(uint4*)&ea16[(size_t)s * 64 + q8 * 8] = *(uint4*)tmp;
    }
  }
}

// ---------------- per-layer node-side precompute, bf16 out ----------------
// up16[n] = [u(64) | p(64)] bf16 ; v16[n] = v(64) bf16
__global__ __launch_bounds__(256) void k_node_pre(
    const float* __restrict__ xemb, const float* __restrict__ eW1,
    const float* __restrict__ nW1, unsigned short* __restrict__ up16,
    unsigned short* __restrict__ v16, int N) {
  __shared__ float sWa[64 * 64];
  __shared__ float sWb[64 * 64];
  __shared__ float sWp[64 * 64];
  for (int i = threadIdx.x; i < 64 * 64; i += blockDim.x) {
    sWa[i] = eW1[i];
    sWb[i] = eW1[64 * 64 + i];
    sWp[i] = nW1[i];
  }
  __syncthreads();
  int stride = gridDim.x * blockDim.x;
  for (int n = blockIdx.x * blockDim.x + threadIdx.x; n < N; n += stride) {
    const float4* xr4 = (const float4*)(xemb + (size_t)n * 64);
    float u[64], p[64];
#pragma unroll
    for (int j = 0; j < 64; ++j) { u[j] = 0.f; p[j] = 0.f; }
    for (int k4 = 0; k4 < 16; ++k4) {
      float4 av = xr4[k4];
      const float* wa = sWa + k4 * 256;
      const float* wp = sWp + k4 * 256;
#pragma unroll
      for (int j = 0; j < 64; ++j) u[j] = fmaf(av.x, wa[j], u[j]);
#pragma unroll
      for (int j = 0; j < 64; ++j) p[j] = fmaf(av.x, wp[j], p[j]);
#pragma unroll
      for (int j = 0; j < 64; ++j) u[j] = fmaf(av.y, wa[64 + j], u[j]);
#pragma unroll
      for (int j = 0; j < 64; ++j) p[j] = fmaf(av.y, wp[64 + j], p[j]);
#pragma unroll
      for (int j = 0; j < 64; ++j) u[j] = fmaf(av.z, wa[128 + j], u[j]);
#pragma unroll
      for (int j = 0; j < 64; ++j) p[j] = fmaf(av.z, wp[128 + j], p[j]);
#pragma unroll
      for (int j = 0; j < 64; ++j) u[j] = fmaf(av.w, wa[192 + j], u[j]);
#pragma unroll
      for (int j = 0; j < 64; ++j) p[j] = fmaf(av.w, wp[192 + j], p[j]);
    }
    unsigned short* o = up16 + (size_t)n * 128;
#pragma unroll
    for (int q8 = 0; q8 < 8; ++q8) {
      unsigned short tmp[8];
#pragma unroll
      for (int j = 0; j < 8; ++j) tmp[j] = f2bf(u[q8 * 8 + j]);
      *(uint4*)&o[q8 * 8] = *(uint4*)tmp;
    }
#pragma unroll
    for (int q8 = 0; q8 < 8; ++q8) {
      unsigned short tmp[8];
#pragma unroll
      for (int j = 0; j < 8; ++j) tmp[j] = f2bf(p[q8 * 8 + j]);
      *(uint4*)&o[64 + q8 * 8] = *(uint4*)tmp;
    }
    float vv[64];
#pragma unroll
    for (int j = 0; j < 64; ++j) vv[j] = 0.f;
    for (int k4 = 0; k4 < 16; ++k4) {
      float4 av = xr4[k4];
      const float* wb = sWb + k4 * 256;
#pragma unroll
      for (int j = 0; j < 64; ++j) vv[j] = fmaf(av.x, wb[j], vv[j]);
#pragma unroll
      for (int j = 0; j < 64; ++j) vv[j] = fmaf(av.y, wb[64 + j], vv[j]);
#pragma unroll
      for (int j = 0; j < 64; ++j) vv[j] = fmaf(av.z, wb[128 + j], vv[j]);
#pragma unroll
      for (int j = 0; j < 64; ++j) vv[j] = fmaf(av.w, wb[192 + j], vv[j]);
    }
    unsigned short* ov = v16 + (size_t)n * 64;
#pragma unroll
    for (int q8 = 0; q8 < 8; ++q8) {
      unsigned short tmp[8];
#pragma unroll
      for (int j = 0; j < 8; ++j) tmp[j] = f2bf(vv[q8 * 8 + j]);
      *(uint4*)&ov[q8 * 8] = *(uint4*)tmp;
    }
  }
}

// ---------------- fused per-layer edge kernel, MFMA bf16 ----------------
#define READ_FRAGS(P)                                                        \
  {                                                                          \
    const v8s* wp_ = (const v8s*)(sWf + (P) * 4096);                         \
    _Pragma("unroll") for (int ct = 0; ct < 4; ++ct)                         \
        _Pragma("unroll") for (int kh = 0; kh < 2; ++kh)                     \
            bfr[ct][kh] = wp_[(ct * 2 + kh) * 64 + l];                       \
    _Pragma("unroll") for (int rb = 0; rb < 2; ++rb)                         \
        _Pragma("unroll") for (int kh = 0; kh < 2; ++kh) {                   \
      int row_ = rbase + rb * 16 + c16;                                      \
      af[rb][kh] = *(const v8s*)&sA[row_ * 64 +                              \
                                    ((kh * 32 + q * 8) ^ ((row_ & 7) << 3))];\
    }                                                                        \
  }

#define DO_MFMA()                                                            \
  _Pragma("unroll") for (int rb = 0; rb < 2; ++rb)                           \
      _Pragma("unroll") for (int ct = 0; ct < 4; ++ct) {                     \
    v4f a_ = {0.f, 0.f, 0.f, 0.f};                                           \
    a_ = __builtin_amdgcn_mfma_f32_16x16x32_bf16(af[rb][0], bfr[ct][0], a_,  \
                                                 0, 0, 0);                   \
    a_ = __builtin_amdgcn_mfma_f32_16x16x32_bf16(af[rb][1], bfr[ct][1], a_,  \
                                                 0, 0, 0);                   \
    acc[rb][ct] = a_;                                                        \
  }

__global__ __launch_bounds__(256, 3) void k_edge_mfma(
    const int* __restrict__ row_s, const int* __restrict__ col_s,
    unsigned short* __restrict__ ea16, const unsigned short* __restrict__ up16,
    const unsigned short* __restrict__ v16, const float* __restrict__ W1c,
    const float* __restrict__ eb1, const float* __restrict__ eW2,
    const float* __restrict__ eb2, const float* __restrict__ nW1b,
    const float* __restrict__ nb1, const float* __restrict__ nW2,
    const float* __restrict__ nb2, float* __restrict__ xnew, int E) {
  // carved shared memory; msgbuf (32KB fp32) aliases sWf (dead after phase 3)
  __shared__ __align__(16) unsigned char smem[50816];
  unsigned short* sWf = (unsigned short*)smem;            // 32 KB
  unsigned short* sA  = (unsigned short*)(smem + 32768);  // 16 KB
  float* sBb          = (float*)(smem + 49152);           // 1 KB
  int* scol           = (int*)(smem + 50176);             // 512 B
  float* msgb         = (float*)smem;                     // alias of sWf

  int tid = threadIdx.x;
  int te = blockIdx.x * 128;

  // weights -> B-fragment layout
  for (int f = tid; f < 4096; f += 256) {
    int j = f & 7, ln = (f >> 3) & 63, kh = (f >> 9) & 1, ct = f >> 10;
    int k = kh * 32 + (ln >> 4) * 8 + j;
    int n = ct * 16 + (ln & 15);
    int wi = k * 64 + n;
    sWf[f] = f2bf(W1c[wi]);
    sWf[4096 + f] = f2bf(eW2[wi]);
    sWf[8192 + f] = f2bf(nW1b[wi]);
    sWf[12288 + f] = f2bf(nW2[wi]);
  }
  if (tid < 64) {
    sBb[0 * 64 + tid] = eb1[tid];
    sBb[1 * 64 + tid] = eb2[tid];
    sBb[2 * 64 + tid] = nb1[tid];
    sBb[3 * 64 + tid] = nb2[tid];
  }
  if (tid < 128) {
    int e = te + tid;
    scol[tid] = col_s[e < E ? e : E - 1];
  }
  // A tile (ea bf16), XOR-swizzled
  for (int i = tid; i < 1024; i += 256) {
    int r = i >> 3, cc = i & 7;
    int e = te + r;
    if (e >= E) e = E - 1;
    uint4 d = *(const uint4*)&ea16[(size_t)e * 64 + cc * 8];
    *(uint4*)&sA[r * 64 + ((cc * 8) ^ ((r & 7) << 3))] = d;
  }

  int w = tid >> 6, l = tid & 63, q = l >> 4, c16 = l & 15;
  int rbase = w * 32;

  int rid[2][4], cid[2][4], eid[2][4];
#pragma unroll
  for (int rb = 0; rb < 2; ++rb)
#pragma unroll
    for (int r = 0; r < 4; ++r) {
      int rit = rbase + rb * 16 + q * 4 + r;
      int e = te + rit;
      eid[rb][r] = e;
      int ec = e < E ? e : E - 1;
      rid[rb][r] = row_s[ec];
      cid[rb][r] = col_s[ec];
    }

  v8s af[2][2];
  v8s bfr[4][2];
  v4f acc[2][4];

  // ---- phase 0: T = sp(ea@W1c + b1 + u[row] + v[col]) ----
  __syncthreads();
  READ_FRAGS(0);
  __syncthreads();
  DO_MFMA();
#pragma unroll
  for (int rb = 0; rb < 2; ++rb)
#pragma unroll
    for (int ct = 0; ct < 4; ++ct) {
      int n = ct * 16 + c16;
#pragma unroll
      for (int r = 0; r < 4; ++r) {
        float t = acc[rb][ct][r] + sBb[n] +
                  bf2f(up16[(size_t)rid[rb][r] * 128 + n]) +
                  bf2f(v16[(size_t)cid[rb][r] * 64 + n]);
        t = sp_f(t);
        int row = rbase + rb * 16 + q * 4 + r;
        sA[row * 64 + (n ^ ((row & 7) << 3))] = f2bf(t);
      }
    }

  // ---- phase 1: ea' = T@eW2 + b2 ----
  __syncthreads();
  READ_FRAGS(1);
  __syncthreads();
  DO_MFMA();
#pragma unroll
  for (int rb = 0; rb < 2; ++rb)
#pragma unroll
    for (int ct = 0; ct < 4; ++ct) {
      int n = ct * 16 + c16;
#pragma unroll
      for (int r = 0; r < 4; ++r) {
        float en = acc[rb][ct][r] + sBb[64 + n];
        unsigned short h = f2bf(en);
        int row = rbase + rb * 16 + q * 4 + r;
        sA[row * 64 + (n ^ ((row & 7) << 3))] = h;
        if (eid[rb][r] < E) ea16[(size_t)eid[rb][r] * 64 + n] = h;
      }
    }

  // ---- phase 2: T2 = sp(ea'@nW1b + b3 + p[row]) ----
  __syncthreads();
  READ_FRAGS(2);
  __syncthreads();
  DO_MFMA();
#pragma unroll
  for (int rb = 0; rb < 2; ++rb)
#pragma unroll
    for (int ct = 0; ct < 4; ++ct) {
      int n = ct * 16 + c16;
#pragma unroll
      for (int r = 0; r < 4; ++r) {
        float t2 = acc[rb][ct][r] + sBb[128 + n] +
                   bf2f(up16[(size_t)rid[rb][r] * 128 + 64 + n]);
        t2 = sp_f(t2);
        int row = rbase + rb * 16 + q * 4 + r;
        sA[row * 64 + (n ^ ((row & 7) << 3))] = f2bf(t2);
      }
    }

  // ---- phase 3: msg = T2@nW2 + b4 -> LDS (weights now dead) ----
  __syncthreads();
  READ_FRAGS(3);
  __syncthreads();   // all waves done reading sWf; safe to overwrite as msgb
  DO_MFMA();
#pragma unroll
  for (int rb = 0; rb < 2; ++rb)
#pragma unroll
    for (int ct = 0; ct < 4; ++ct) {
      int n = ct * 16 + c16;
#pragma unroll
      for (int r = 0; r < 4; ++r) {
        float msg = acc[rb][ct][r] + sBb[192 + n];
        int row = rbase + rb * 16 + q * 4 + r;
        msgb[row * 64 + n] = (eid[rb][r] < E) ? msg : 0.0f;
      }
    }
  __syncthreads();

  // ---- segmented reduction over col-runs; one atomic per (segment, channel) ----
  int nrows = E - te;
  if (nrows > 128) nrows = 128;
  for (int r0 = w; r0 < nrows; r0 += 4) {
    int c0 = scol[r0];
    if (r0 > 0 && scol[r0 - 1] == c0) continue;  // not a segment start (uniform)
    float s = 0.0f;
    int r = r0;
    do {
      s += msgb[r * 64 + l];
      ++r;
    } while (r < nrows && scol[r] == c0);
    atomicAdd(&xnew[(size_t)c0 * 64 + l], s);
  }
}

// ---------------- BN stats ----------------
__global__ __launch_bounds__(256) void k_bn_stats(
    const float* __restrict__ xnew, float* __restrict__ bnacc, int N) {
  int t = threadIdx.x;
  int ch = t & 63;
  int sl = t >> 6;
  float s = 0.f, s2 = 0.f;
  for (int n = blockIdx.x * 4 + sl; n < N; n += gridDim.x * 4) {
    float v = xnew[(size_t)n * 64 + ch];
    s += v;
    s2 = fmaf(v, v, s2);
  }
  __shared__ float red[256], red2[256];
  red[t] = s;
  red2[t] = s2;
  __syncthreads();
  if (sl == 0) {
    s = red[ch] + red[64 + ch] + red[128 + ch] + red[192 + ch];
    s2 = red2[ch] + red2[64 + ch] + red2[128 + ch] + red2[192 + ch];
    atomicAdd(&bnacc[ch], s);
    atomicAdd(&bnacc[64 + ch], s2);
  }
}

// ---------------- BN apply + softplus + residual ----------------
__global__ __launch_bounds__(256) void k_bn_apply(
    float* __restrict__ x, const float* __restrict__ xnew,
    const float* __restrict__ bnacc, const float* __restrict__ gamma,
    const float* __restrict__ beta, int N) {
  __shared__ float sscale[64], sshift[64];
  if (threadIdx.x < 64) {
    float inv = 1.0f / (float)N;
    float m = bnacc[threadIdx.x] * inv;
    float var = bnacc[64 + threadIdx.x] * inv - m * m;
    float rs = rsqrtf(var + 1e-5f);
    float g = gamma[threadIdx.x];
    sscale[threadIdx.x] = rs * g;
    sshift[threadIdx.x] = beta[threadIdx.x] - m * rs * g;
  }
  __syncthreads();
  size_t total = (size_t)N * 64;
  size_t stride = (size_t)gridDim.x * blockDim.x;
  for (size_t i = (size_t)blockIdx.x * blockDim.x + threadIdx.x; i < total; i += stride) {
    int ch = (int)(i & 63);
    float v = fmaf(xnew[i], sscale[ch], sshift[ch]);
    x[i] += sp_f(v);
  }
}

// ---------------- pool + predictor ----------------
__device__ __forceinline__ int lbound(const int* a, int n, int key) {
  int lo = 0, hi = n;
  while (lo < hi) {
    int mid = (lo + hi) >> 1;
    if (a[mid] < key) lo = mid + 1; else hi = mid;
  }
  return lo;
}

__global__ __launch_bounds__(256) void k_pool(
    const float* __restrict__ x, const int* __restrict__ batch, int N,
    float* __restrict__ g) {
  int b = blockIdx.x;
  int lo = lbound(batch, N, b);
  int hi = lbound(batch, N, b + 1);
  int t = threadIdx.x;
  int ch = t & 63;
  int sl = t >> 6;
  float s = 0.f;
  for (int n = lo + sl; n < hi; n += 4) s += x[(size_t)n * 64 + ch];
  __shared__ float red[4][64];
  red[sl][ch] = s;
  __syncthreads();
  if (t < 64) {
    float tot = red[0][t] + red[1][t] + red[2][t] + red[3][t];
    float cnt = (float)(hi - lo);
    g[(size_t)b * 64 + t] = tot / fmaxf(cnt, 1.0f);
  }
}

__global__ __launch_bounds__(128) void k_pred(
    const float* __restrict__ g, const float* __restrict__ pW1,
    const float* __restrict__ pb1, const float* __restrict__ pW2,
    const float* __restrict__ pb2, const float* __restrict__ pW3,
    const float* __restrict__ pb3, float* __restrict__ out) {
  int b = blockIdx.x;
  int t = threadIdx.x;
  __shared__ float sg[64];
  __shared__ float sh1[128];
  __shared__ float red[128];
  if (t < 64) sg[t] = g[(size_t)b * 64 + t];
  __syncthreads();
  float s = pb1[t];
  for (int k = 0; k < 64; ++k) s = fmaf(sg[k], pW1[k * 128 + t], s);
  sh1[t] = sp_f(s);
  __syncthreads();
  s = pb2[t];
  for (int k = 0; k < 128; ++k) s = fmaf(sh1[k], pW2[k * 128 + t], s);
  float h2 = sp_f(s);
  red[t] = h2 * pW3[t];
  __syncthreads();
  for (int off = 64; off > 0; off >>= 1) {
    if (t < off) red[t] += red[t + off];
    __syncthreads();
  }
  if (t == 0) out[b] = red[0] + pb3[0];
}

extern "C" void kernel_launch(void* const* d_in, const int* in_sizes, int n_in,
                              void* d_out, int out_size, void* d_ws, size_t ws_size,
                              hipStream_t stream) {
  const float* x         = (const float*)d_in[0];
  const float* edge_attr = (const float*)d_in[1];
  const float* charge    = (const float*)d_in[2];
  const int*   eidx      = (const int*)d_in[3];
  const int*   batch     = (const int*)d_in[4];
  const float* W_charge  = (const float*)d_in[5];
  const float* b_charge  = (const float*)d_in[6];
  const float* W_atom    = (const float*)d_in[7];
  const float* b_atom    = (const float*)d_in[8];
  const float* W_bond    = (const float*)d_in[9];
  const float* b_bond    = (const float*)d_in[10];
  const float* eW1 = (const float*)d_in[11];
  const float* eb1 = (const float*)d_in[12];
  const float* eW2 = (const float*)d_in[13];
  const float* eb2 = (const float*)d_in[14];
  const float* nW1 = (const float*)d_in[15];
  const float* nb1 = (const float*)d_in[16];
  const float* nW2 = (const float*)d_in[17];
  const float* nb2 = (const float*)d_in[18];
  const float* gam = (const float*)d_in[19];
  const float* bet = (const float*)d_in[20];
  const float* pW1 = (const float*)d_in[21];
  const float* pb1 = (const float*)d_in[22];
  const float* pW2 = (const float*)d_in[23];
  const float* pb2 = (const float*)d_in[24];
  const float* pW3 = (const float*)d_in[25];
  const float* pb3 = (const float*)d_in[26];

  int N = in_sizes[4];
  int E = in_sizes[3] / 2;
  int B = in_sizes[2];
  const int* row = eidx;
  const int* col = eidx + E;

  char* wptr = (char*)d_ws;
  unsigned short* ea16 = (unsigned short*)wptr; wptr += (((size_t)E * 64 * 2 + 255) & ~255ull);
  unsigned short* up16 = (unsigned short*)wptr; wptr += (((size_t)N * 128 * 2 + 255) & ~255ull);
  unsigned short* v16  = (unsigned short*)wptr; wptr += (((size_t)N * 64 * 2 + 255) & ~255ull);
  float* xemb = (float*)wptr; wptr += (size_t)N * 64 * 4;
  float* xnew = (float*)wptr; wptr += (size_t)N * 64 * 4;
  float* gbuf = (float*)wptr; wptr += (size_t)B * 64 * 4;
  float* bnacc = (float*)wptr; wptr += 256 * 4;
  int* counts = (int*)wptr;   wptr += (size_t)N * 4;
  int* scan_tmp = (int*)wptr; wptr += (size_t)N * 4;
  int* cursor = (int*)wptr;   wptr += (size_t)N * 4;
  int* bsum = (int*)wptr;     wptr += 4096;
  int* perm = (int*)wptr;     wptr += (size_t)E * 4;
  int* row_s = (int*)wptr;    wptr += (size_t)E * 4;
  int* col_s = (int*)wptr;    wptr += (size_t)E * 4;

  int NB = (N + 255) / 256;

  hipMemsetAsync(counts, 0, (size_t)N * 4, stream);
  k_hist<<<2048, 256, 0, stream>>>(col, counts, E);
  k_scan1<<<NB, 256, 0, stream>>>(counts, scan_tmp, bsum, N);
  k_scan2<<<1, 256, 0, stream>>>(bsum, NB);
  k_scan3<<<NB, 256, 0, stream>>>(counts, scan_tmp, bsum, cursor, N);
  k_scatter<<<2048, 256, 0, stream>>>(row, col, cursor, perm, row_s, col_s, E);

  k_embed_nodes<<<NB, 256, 0, stream>>>(x, batch, charge, W_charge, b_charge,
                                        W_atom, b_atom, xemb, N);
  k_embed_bonds_perm<<<4096, 256, 0, stream>>>(edge_attr, perm, W_bond, b_bond,
                                               ea16, E);

  int gridE = (E + 127) / 128;
  for (int i = 0; i < 3; ++i) {
    const float* leW1 = eW1 + (size_t)i * 192 * 64;
    const float* leb1 = eb1 + (size_t)i * 64;
    const float* leW2 = eW2 + (size_t)i * 64 * 64;
    const float* leb2 = eb2 + (size_t)i * 64;
    const float* lnW1 = nW1 + (size_t)i * 128 * 64;
    const float* lnb1 = nb1 + (size_t)i * 64;
    const float* lnW2 = nW2 + (size_t)i * 64 * 64;
    const float* lnb2 = nb2 + (size_t)i * 64;

    k_node_pre<<<NB, 256, 0, stream>>>(xemb, leW1, lnW1, up16, v16, N);
    hipMemsetAsync(xnew, 0, (size_t)N * 64 * 4, stream);
    hipMemsetAsync(bnacc, 0, 256 * 4, stream);
    k_edge_mfma<<<gridE, 256, 0, stream>>>(row_s, col_s, ea16, up16, v16,
                                           leW1 + 128 * 64, leb1, leW2, leb2,
                                           lnW1 + 64 * 64, lnb1, lnW2, lnb2,
                                           xnew, E);
    k_bn_stats<<<1024, 256, 0, stream>>>(xnew, bnacc, N);
    k_bn_apply<<<4096, 256, 0, stream>>>(xemb, xnew, bnacc, gam + (size_t)i * 64,
                                         bet + (size_t)i * 64, N);
  }

  k_pool<<<B, 256, 0, stream>>>(xemb, batch, N, gbuf);
  k_pred<<<B, 128, 0, stream>>>(gbuf, pW1, pb1, pW2, pb2, pW3, pb3, (float*)d_out);
}

// Round 4
// 2533.857 us; speedup vs baseline: 7.8872x; 1.0631x over previous
//
#include <hip/hip_runtime.h>
#include <math.h>

typedef short v8s __attribute__((ext_vector_type(8)));   // 8 bf16
typedef float v4f __attribute__((ext_vector_type(4)));

// fast softplus: max(x,0) + ln2*log2(1+exp(-|x|)); HW exp/log, ~3e-5 abs err
__device__ __forceinline__ float sp_f(float x) {
  return fmaxf(x, 0.0f) + 0.69314718056f * __log2f(1.0f + __expf(-fabsf(x)));
}

__device__ __forceinline__ unsigned short f2bf(float f) {
  union { float f; unsigned u; } x; x.f = f;
  unsigned r = (x.u + 0x7FFF + ((x.u >> 16) & 1)) >> 16;
  return (unsigned short)r;
}

__device__ __forceinline__ float bf2f(unsigned short h) {
  union { unsigned u; float f; } x; x.u = ((unsigned)h) << 16;
  return x.f;
}

// ---------------- node embedding (fp32) ----------------
__global__ __launch_bounds__(256) void k_embed_nodes(
    const float* __restrict__ x, const int* __restrict__ batch,
    const float* __restrict__ charge, const float* __restrict__ W_charge,
    const float* __restrict__ b_charge, const float* __restrict__ W_atom,
    const float* __restrict__ b_atom, float* __restrict__ xemb, int N) {
  __shared__ float sW[108 * 64];
  __shared__ float sb[64];
  __shared__ float sWc[16];
  __shared__ float sbc[16];
  for (int i = threadIdx.x; i < 108 * 64; i += blockDim.x) sW[i] = W_atom[i];
  if (threadIdx.x < 64) sb[threadIdx.x] = b_atom[threadIdx.x];
  if (threadIdx.x < 16) {
    sWc[threadIdx.x] = W_charge[threadIdx.x];
    sbc[threadIdx.x] = b_charge[threadIdx.x];
  }
  __syncthreads();
  int stride = gridDim.x * blockDim.x;
  for (int n = blockIdx.x * blockDim.x + threadIdx.x; n < N; n += stride) {
    float acc[64];
#pragma unroll
    for (int j = 0; j < 64; ++j) acc[j] = sb[j];
    const float* xr = x + (size_t)n * 92;
    for (int k = 0; k < 92; ++k) {
      float a = xr[k];
      const float* w = sW + k * 64;
#pragma unroll
      for (int j = 0; j < 64; ++j) acc[j] = fmaf(a, w[j], acc[j]);
    }
    float ch = charge[batch[n]];
#pragma unroll
    for (int c = 0; c < 16; ++c) {
      float cf = fmaf(ch, sWc[c], sbc[c]);
      const float* w = sW + (92 + c) * 64;
#pragma unroll
      for (int j = 0; j < 64; ++j) acc[j] = fmaf(cf, w[j], acc[j]);
    }
    float* o = xemb + (size_t)n * 64;
#pragma unroll
    for (int q = 0; q < 16; ++q)
      ((float4*)o)[q] = make_float4(acc[4*q], acc[4*q+1], acc[4*q+2], acc[4*q+3]);
  }
}

// ---------------- CSR build ----------------
__global__ __launch_bounds__(256) void k_hist(const int* __restrict__ col,
                                              int* __restrict__ counts, int E) {
  int stride = gridDim.x * blockDim.x;
  for (int e = blockIdx.x * blockDim.x + threadIdx.x; e < E; e += stride)
    atomicAdd(&counts[col[e]], 1);
}

__global__ __launch_bounds__(256) void k_scan1(const int* __restrict__ counts,
                                               int* __restrict__ scan_tmp,
                                               int* __restrict__ bsum, int N) {
  __shared__ int sd[2][256];
  int t = threadIdx.x;
  int i = blockIdx.x * 256 + t;
  int v = (i < N) ? counts[i] : 0;
  sd[0][t] = v;
  __syncthreads();
  int s = 0;
#pragma unroll
  for (int off = 1; off < 256; off <<= 1) {
    int nv = sd[s][t];
    if (t >= off) nv += sd[s][t - off];
    sd[s ^ 1][t] = nv;
    s ^= 1;
    __syncthreads();
  }
  if (i < N) scan_tmp[i] = sd[s][t];
  if (t == 255) bsum[blockIdx.x] = sd[s][255];
}

__global__ __launch_bounds__(256) void k_scan2(int* __restrict__ b, int NB) {
  __shared__ int sd[2][256];
  __shared__ int carry_s;
  int t = threadIdx.x;
  if (t == 0) carry_s = 0;
  __syncthreads();
  for (int base = 0; base < NB; base += 256) {
    int i = base + t;
    int v = (i < NB) ? b[i] : 0;
    sd[0][t] = v;
    __syncthreads();
    int s = 0;
#pragma unroll
    for (int off = 1; off < 256; off <<= 1) {
      int nv = sd[s][t];
      if (t >= off) nv += sd[s][t - off];
      sd[s ^ 1][t] = nv;
      s ^= 1;
      __syncthreads();
    }
    int c = carry_s;
    int tot = sd[s][255];
    if (i < NB) b[i] = sd[s][t] + c;
    __syncthreads();
    if (t == 0) carry_s = c + tot;
    __syncthreads();
  }
}

__global__ __launch_bounds__(256) void k_scan3(const int* __restrict__ counts,
                                               const int* __restrict__ scan_tmp,
                                               const int* __restrict__ bsum,
                                               int* __restrict__ cursor, int N) {
  int i = blockIdx.x * 256 + threadIdx.x;
  if (i < N) {
    int base = (blockIdx.x > 0) ? bsum[blockIdx.x - 1] : 0;
    cursor[i] = scan_tmp[i] - counts[i] + base;
  }
}

// writes pos[e] = sorted position (inverse permutation) + row_s/col_s
__global__ __launch_bounds__(256) void k_scatter(
    const int* __restrict__ row, const int* __restrict__ col,
    int* __restrict__ cursor, int* __restrict__ pos,
    int* __restrict__ row_s, int* __restrict__ col_s, int E) {
  int stride = gridDim.x * blockDim.x;
  for (int e = blockIdx.x * blockDim.x + threadIdx.x; e < E; e += stride) {
    int c = col[e];
    int p = atomicAdd(&cursor[c], 1);
    pos[e] = p;
    row_s[p] = row[e];
    col_s[p] = c;
  }
}

// ---------------- bond embedding: coalesced read, scatter write ----------------
__global__ __launch_bounds__(256) void k_embed_bonds_pos(
    const float* __restrict__ eattr, const int* __restrict__ pos,
    const float* __restrict__ W_bond, const float* __restrict__ b_bond,
    unsigned short* __restrict__ ea16, int E) {
  __shared__ float sW[41 * 64];
  __shared__ float sb[64];
  for (int i = threadIdx.x; i < 41 * 64; i += blockDim.x) sW[i] = W_bond[i];
  if (threadIdx.x < 64) sb[threadIdx.x] = b_bond[threadIdx.x];
  __syncthreads();
  int stride = gridDim.x * blockDim.x;
  for (int e = blockIdx.x * blockDim.x + threadIdx.x; e < E; e += stride) {
    float acc[64];
#pragma unroll
    for (int j = 0; j < 64; ++j) acc[j] = sb[j];
    const float* er = eattr + (size_t)e * 41;
    for (int k = 0; k < 41; ++k) {
      float a = er[k];
      const float* w = sW + k * 64;
#pragma unroll
      for (int j = 0; j < 64; ++j) acc[j] = fmaf(a, w[j], acc[j]);
    }
    size_t ob = (size_t)pos[e] * 64;
#pragma unroll
    for (int q8 = 0; q8 < 8; ++q8) {
      unsigned short tmp[8];
#pragma unroll
      for (int j = 0; j < 8; ++j) tmp[j] = f2bf(acc[q8 * 8 + j]);
      *(uint4*)&ea16[ob + q8 * 8] = *(uint4*)tmp;
    }
  }
}

// ---------------- per-layer node-side precompute, bf16 out, channel-permuted ----
// storage index for channel ch: (ch&15)*4 + (ch>>4)  => lane c16 reads ushort4
// at [c16*4] giving channels {0,16,32,48}+c16 (ct = 0..3)
__global__ __launch_bounds__(256) void k_node_pre(
    const float* __restrict__ xemb, const float* __restrict__ eW1,
    const float* __restrict__ nW1, unsigned short* __restrict__ up16,
    unsigned short* __restrict__ v16, int N) {
  __shared__ float sWa[64 * 64];
  __shared__ float sWb[64 * 64];
  __shared__ float sWp[64 * 64];
  for (int i = threadIdx.x; i < 64 * 64; i += blockDim.x) {
    sWa[i] = eW1[i];
    sWb[i] = eW1[64 * 64 + i];
    sWp[i] = nW1[i];
  }
  __syncthreads();
  int stride = gridDim.x * blockDim.x;
  for (int n = blockIdx.x * blockDim.x + threadIdx.x; n < N; n += stride) {
    const float4* xr4 = (const float4*)(xemb + (size_t)n * 64);
    float u[64], p[64];
#pragma unroll
    for (int j = 0; j < 64; ++j) { u[j] = 0.f; p[j] = 0.f; }
    for (int k4 = 0; k4 < 16; ++k4) {
      float4 av = xr4[k4];
      const float* wa = sWa + k4 * 256;
      const float* wp = sWp + k4 * 256;
#pragma unroll
      for (int j = 0; j < 64; ++j) u[j] = fmaf(av.x, wa[j], u[j]);
#pragma unroll
      for (int j = 0; j < 64; ++j) p[j] = fmaf(av.x, wp[j], p[j]);
#pragma unroll
      for (int j = 0; j < 64; ++j) u[j] = fmaf(av.y, wa[64 + j], u[j]);
#pragma unroll
      for (int j = 0; j < 64; ++j) p[j] = fmaf(av.y, wp[64 + j], p[j]);
#pragma unroll
      for (int j = 0; j < 64; ++j) u[j] = fmaf(av.z, wa[128 + j], u[j]);
#pragma unroll
      for (int j = 0; j < 64; ++j) p[j] = fmaf(av.z, wp[128 + j], p[j]);
#pragma unroll
      for (int j = 0; j < 64; ++j) u[j] = fmaf(av.w, wa[192 + j], u[j]);
#pragma unroll
      for (int j = 0; j < 64; ++j) p[j] = fmaf(av.w, wp[192 + j], p[j]);
    }
    // write permuted: out[i] = val[((i&3)<<4) | (i>>2)]
    unsigned short* o = up16 + (size_t)n * 128;
#pragma unroll
    for (int q8 = 0; q8 < 8; ++q8) {
      unsigned short tmp[8];
#pragma unroll
      for (int j = 0; j < 8; ++j) {
        int i = q8 * 8 + j;
        tmp[j] = f2bf(u[((i & 3) << 4) | (i >> 2)]);
      }
      *(uint4*)&o[q8 * 8] = *(uint4*)tmp;
    }
#pragma unroll
    for (int q8 = 0; q8 < 8; ++q8) {
      unsigned short tmp[8];
#pragma unroll
      for (int j = 0; j < 8; ++j) {
        int i = q8 * 8 + j;
        tmp[j] = f2bf(p[((i & 3) << 4) | (i >> 2)]);
      }
      *(uint4*)&o[64 + q8 * 8] = *(uint4*)tmp;
    }
    float vv[64];
#pragma unroll
    for (int j = 0; j < 64; ++j) vv[j] = 0.f;
    for (int k4 = 0; k4 < 16; ++k4) {
      float4 av = xr4[k4];
      const float* wb = sWb + k4 * 256;
#pragma unroll
      for (int j = 0; j < 64; ++j) vv[j] = fmaf(av.x, wb[j], vv[j]);
#pragma unroll
      for (int j = 0; j < 64; ++j) vv[j] = fmaf(av.y, wb[64 + j], vv[j]);
#pragma unroll
      for (int j = 0; j < 64; ++j) vv[j] = fmaf(av.z, wb[128 + j], vv[j]);
#pragma unroll
      for (int j = 0; j < 64; ++j) vv[j] = fmaf(av.w, wb[192 + j], vv[j]);
    }
    unsigned short* ov = v16 + (size_t)n * 64;
#pragma unroll
    for (int q8 = 0; q8 < 8; ++q8) {
      unsigned short tmp[8];
#pragma unroll
      for (int j = 0; j < 8; ++j) {
        int i = q8 * 8 + j;
        tmp[j] = f2bf(vv[((i & 3) << 4) | (i >> 2)]);
      }
      *(uint4*)&ov[q8 * 8] = *(uint4*)tmp;
    }
  }
}

// ---------------- fused per-layer edge kernel, MFMA bf16 ----------------
#define READ_FRAGS(P)                                                        \
  {                                                                          \
    const v8s* wp_ = (const v8s*)(sWf + (P) * 4096);                         \
    _Pragma("unroll") for (int ct = 0; ct < 4; ++ct)                         \
        _Pragma("unroll") for (int kh = 0; kh < 2; ++kh)                     \
            bfr[ct][kh] = wp_[(ct * 2 + kh) * 64 + l];                       \
    _Pragma("unroll") for (int rb = 0; rb < 2; ++rb)                         \
        _Pragma("unroll") for (int kh = 0; kh < 2; ++kh) {                   \
      int row_ = rbase + rb * 16 + c16;                                      \
      af[rb][kh] = *(const v8s*)&sA[row_ * 64 +                              \
                                    ((kh * 32 + q * 8) ^ ((row_ & 7) << 3))];\
    }                                                                        \
  }

#define DO_MFMA()                                                            \
  _Pragma("unroll") for (int rb = 0; rb < 2; ++rb)                           \
      _Pragma("unroll") for (int ct = 0; ct < 4; ++ct) {                     \
    v4f a_ = {0.f, 0.f, 0.f, 0.f};                                           \
    a_ = __builtin_amdgcn_mfma_f32_16x16x32_bf16(af[rb][0], bfr[ct][0], a_,  \
                                                 0, 0, 0);                   \
    a_ = __builtin_amdgcn_mfma_f32_16x16x32_bf16(af[rb][1], bfr[ct][1], a_,  \
                                                 0, 0, 0);                   \
    acc[rb][ct] = a_;                                                        \
  }

__global__ __launch_bounds__(256, 3) void k_edge_mfma(
    const int* __restrict__ row_s, const int* __restrict__ col_s,
    unsigned short* __restrict__ ea16, const unsigned short* __restrict__ up16,
    const unsigned short* __restrict__ v16, const float* __restrict__ W1c,
    const float* __restrict__ eb1, const float* __restrict__ eW2,
    const float* __restrict__ eb2, const float* __restrict__ nW1b,
    const float* __restrict__ nb1, const float* __restrict__ nW2,
    const float* __restrict__ nb2, float* __restrict__ xnew, int E) {
  __shared__ __align__(16) unsigned char smem[50816];
  unsigned short* sWf = (unsigned short*)smem;            // 32 KB
  unsigned short* sA  = (unsigned short*)(smem + 32768);  // 16 KB
  float* sBb          = (float*)(smem + 49152);           // 1 KB
  int* scol           = (int*)(smem + 50176);             // 512 B
  float* msgb         = (float*)smem;                     // alias of sWf

  int tid = threadIdx.x;
  int te = blockIdx.x * 128;

  for (int f = tid; f < 4096; f += 256) {
    int j = f & 7, ln = (f >> 3) & 63, kh = (f >> 9) & 1, ct = f >> 10;
    int k = kh * 32 + (ln >> 4) * 8 + j;
    int n = ct * 16 + (ln & 15);
    int wi = k * 64 + n;
    sWf[f] = f2bf(W1c[wi]);
    sWf[4096 + f] = f2bf(eW2[wi]);
    sWf[8192 + f] = f2bf(nW1b[wi]);
    sWf[12288 + f] = f2bf(nW2[wi]);
  }
  if (tid < 64) {
    sBb[0 * 64 + tid] = eb1[tid];
    sBb[1 * 64 + tid] = eb2[tid];
    sBb[2 * 64 + tid] = nb1[tid];
    sBb[3 * 64 + tid] = nb2[tid];
  }
  if (tid < 128) {
    int e = te + tid;
    scol[tid] = col_s[e < E ? e : E - 1];
  }
  for (int i = tid; i < 1024; i += 256) {
    int r = i >> 3, cc = i & 7;
    int e = te + r;
    if (e >= E) e = E - 1;
    uint4 d = *(const uint4*)&ea16[(size_t)e * 64 + cc * 8];
    *(uint4*)&sA[r * 64 + ((cc * 8) ^ ((r & 7) << 3))] = d;
  }

  int w = tid >> 6, l = tid & 63, q = l >> 4, c16 = l & 15;
  int rbase = w * 32;

  int rid[2][4], cid[2][4], eid[2][4];
#pragma unroll
  for (int rb = 0; rb < 2; ++rb)
#pragma unroll
    for (int r = 0; r < 4; ++r) {
      int rit = rbase + rb * 16 + q * 4 + r;
      int e = te + rit;
      eid[rb][r] = e;
      int ec = e < E ? e : E - 1;
      rid[rb][r] = row_s[ec];
      cid[rb][r] = col_s[ec];
    }

  v8s af[2][2];
  v8s bfr[4][2];
  v4f acc[2][4];

  // ---- phase 0: T = sp(ea@W1c + b1 + u[row] + v[col]) ----
  __syncthreads();
  READ_FRAGS(0);
  __syncthreads();
  DO_MFMA();
#pragma unroll
  for (int rb = 0; rb < 2; ++rb)
#pragma unroll
    for (int r = 0; r < 4; ++r) {
      ushort4 uu = *(const ushort4*)&up16[(size_t)rid[rb][r] * 128 + c16 * 4];
      ushort4 vv = *(const ushort4*)&v16[(size_t)cid[rb][r] * 64 + c16 * 4];
      int row = rbase + rb * 16 + q * 4 + r;
      const unsigned short* up_ = (const unsigned short*)&uu;
      const unsigned short* vp_ = (const unsigned short*)&vv;
#pragma unroll
      for (int ct = 0; ct < 4; ++ct) {
        int n = ct * 16 + c16;
        float t = acc[rb][ct][r] + sBb[n] + bf2f(up_[ct]) + bf2f(vp_[ct]);
        t = sp_f(t);
        sA[row * 64 + (n ^ ((row & 7) << 3))] = f2bf(t);
      }
    }

  // ---- phase 1: ea' = T@eW2 + b2 -> sA, then coalesced writeback ----
  __syncthreads();
  READ_FRAGS(1);
  __syncthreads();
  DO_MFMA();
#pragma unroll
  for (int rb = 0; rb < 2; ++rb)
#pragma unroll
    for (int ct = 0; ct < 4; ++ct) {
      int n = ct * 16 + c16;
#pragma unroll
      for (int r = 0; r < 4; ++r) {
        float en = acc[rb][ct][r] + sBb[64 + n];
        int row = rbase + rb * 16 + q * 4 + r;
        sA[row * 64 + (n ^ ((row & 7) << 3))] = f2bf(en);
      }
    }
  __syncthreads();
  // coalesced ea' writeback from LDS
  for (int i = tid; i < 1024; i += 256) {
    int r = i >> 3, cc = i & 7;
    if (te + r < E) {
      uint4 d = *(const uint4*)&sA[r * 64 + ((cc * 8) ^ ((r & 7) << 3))];
      *(uint4*)&ea16[(size_t)(te + r) * 64 + cc * 8] = d;
    }
  }

  // ---- phase 2: T2 = sp(ea'@nW1b + b3 + p[row]) ----
  READ_FRAGS(2);
  __syncthreads();
  DO_MFMA();
#pragma unroll
  for (int rb = 0; rb < 2; ++rb)
#pragma unroll
    for (int r = 0; r < 4; ++r) {
      ushort4 pp = *(const ushort4*)&up16[(size_t)rid[rb][r] * 128 + 64 + c16 * 4];
      int row = rbase + rb * 16 + q * 4 + r;
      const unsigned short* pp_ = (const unsigned short*)&pp;
#pragma unroll
      for (int ct = 0; ct < 4; ++ct) {
        int n = ct * 16 + c16;
        float t2 = acc[rb][ct][r] + sBb[128 + n] + bf2f(pp_[ct]);
        t2 = sp_f(t2);
        sA[row * 64 + (n ^ ((row & 7) << 3))] = f2bf(t2);
      }
    }

  // ---- phase 3: msg = T2@nW2 + b4 -> LDS (weights now dead) ----
  __syncthreads();
  READ_FRAGS(3);
  __syncthreads();
  DO_MFMA();
#pragma unroll
  for (int rb = 0; rb < 2; ++rb)
#pragma unroll
    for (int ct = 0; ct < 4; ++ct) {
      int n = ct * 16 + c16;
#pragma unroll
      for (int r = 0; r < 4; ++r) {
        float msg = acc[rb][ct][r] + sBb[192 + n];
        int row = rbase + rb * 16 + q * 4 + r;
        msgb[row * 64 + n] = (eid[rb][r] < E) ? msg : 0.0f;
      }
    }
  __syncthreads();

  // ---- segmented reduction over col-runs; one atomic per (segment, channel) ----
  int nrows = E - te;
  if (nrows > 128) nrows = 128;
  for (int r0 = w; r0 < nrows; r0 += 4) {
    int c0 = scol[r0];
    if (r0 > 0 && scol[r0 - 1] == c0) continue;
    float s = 0.0f;
    int r = r0;
    do {
      s += msgb[r * 64 + l];
      ++r;
    } while (r < nrows && scol[r] == c0);
    atomicAdd(&xnew[(size_t)c0 * 64 + l], s);
  }
}

// ---------------- BN stats ----------------
__global__ __launch_bounds__(256) void k_bn_stats(
    const float* __restrict__ xnew, float* __restrict__ bnacc, int N) {
  int t = threadIdx.x;
  int ch = t & 63;
  int sl = t >> 6;
  float s = 0.f, s2 = 0.f;
  for (int n = blockIdx.x * 4 + sl; n < N; n += gridDim.x * 4) {
    float v = xnew[(size_t)n * 64 + ch];
    s += v;
    s2 = fmaf(v, v, s2);
  }
  __shared__ float red[256], red2[256];
  red[t] = s;
  red2[t] = s2;
  __syncthreads();
  if (sl == 0) {
    s = red[ch] + red[64 + ch] + red[128 + ch] + red[192 + ch];
    s2 = red2[ch] + red2[64 + ch] + red2[128 + ch] + red2[192 + ch];
    atomicAdd(&bnacc[ch], s);
    atomicAdd(&bnacc[64 + ch], s2);
  }
}

// ---------------- BN apply + softplus + residual ----------------
__global__ __launch_bounds__(256) void k_bn_apply(
    float* __restrict__ x, const float* __restrict__ xnew,
    const float* __restrict__ bnacc, const float* __restrict__ gamma,
    const float* __restrict__ beta, int N) {
  __shared__ float sscale[64], sshift[64];
  if (threadIdx.x < 64) {
    float inv = 1.0f / (float)N;
    float m = bnacc[threadIdx.x] * inv;
    float var = bnacc[64 + threadIdx.x] * inv - m * m;
    float rs = rsqrtf(var + 1e-5f);
    float g = gamma[threadIdx.x];
    sscale[threadIdx.x] = rs * g;
    sshift[threadIdx.x] = beta[threadIdx.x] - m * rs * g;
  }
  __syncthreads();
  size_t total = (size_t)N * 64;
  size_t stride = (size_t)gridDim.x * blockDim.x;
  for (size_t i = (size_t)blockIdx.x * blockDim.x + threadIdx.x; i < total; i += stride) {
    int ch = (int)(i & 63);
    float v = fmaf(xnew[i], sscale[ch], sshift[ch]);
    x[i] += sp_f(v);
  }
}

// ---------------- pool + predictor ----------------
__device__ __forceinline__ int lbound(const int* a, int n, int key) {
  int lo = 0, hi = n;
  while (lo < hi) {
    int mid = (lo + hi) >> 1;
    if (a[mid] < key) lo = mid + 1; else hi = mid;
  }
  return lo;
}

__global__ __launch_bounds__(256) void k_pool(
    const float* __restrict__ x, const int* __restrict__ batch, int N,
    float* __restrict__ g) {
  int b = blockIdx.x;
  int lo = lbound(batch, N, b);
  int hi = lbound(batch, N, b + 1);
  int t = threadIdx.x;
  int ch = t & 63;
  int sl = t >> 6;
  float s = 0.f;
  for (int n = lo + sl; n < hi; n += 4) s += x[(size_t)n * 64 + ch];
  __shared__ float red[4][64];
  red[sl][ch] = s;
  __syncthreads();
  if (t < 64) {
    float tot = red[0][t] + red[1][t] + red[2][t] + red[3][t];
    float cnt = (float)(hi - lo);
    g[(size_t)b * 64 + t] = tot / fmaxf(cnt, 1.0f);
  }
}

__global__ __launch_bounds__(128) void k_pred(
    const float* __restrict__ g, const float* __restrict__ pW1,
    const float* __restrict__ pb1, const float* __restrict__ pW2,
    const float* __restrict__ pb2, const float* __restrict__ pW3,
    const float* __restrict__ pb3, float* __restrict__ out) {
  int b = blockIdx.x;
  int t = threadIdx.x;
  __shared__ float sg[64];
  __shared__ float sh1[128];
  __shared__ float red[128];
  if (t < 64) sg[t] = g[(size_t)b * 64 + t];
  __syncthreads();
  float s = pb1[t];
  for (int k = 0; k < 64; ++k) s = fmaf(sg[k], pW1[k * 128 + t], s);
  sh1[t] = sp_f(s);
  __syncthreads();
  s = pb2[t];
  for (int k = 0; k < 128; ++k) s = fmaf(sh1[k], pW2[k * 128 + t], s);
  float h2 = sp_f(s);
  red[t] = h2 * pW3[t];
  __syncthreads();
  for (int off = 64; off > 0; off >>= 1) {
    if (t < off) red[t] += red[t + off];
    __syncthreads();
  }
  if (t == 0) out[b] = red[0] + pb3[0];
}

extern "C" void kernel_launch(void* const* d_in, const int* in_sizes, int n_in,
                              void* d_out, int out_size, void* d_ws, size_t ws_size,
                              hipStream_t stream) {
  const float* x         = (const float*)d_in[0];
  const float* edge_attr = (const float*)d_in[1];
  const float* charge    = (const float*)d_in[2];
  const int*   eidx      = (const int*)d_in[3];
  const int*   batch     = (const int*)d_in[4];
  const float* W_charge  = (const float*)d_in[5];
  const float* b_charge  = (const float*)d_in[6];
  const float* W_atom    = (const float*)d_in[7];
  const float* b_atom    = (const float*)d_in[8];
  const float* W_bond    = (const float*)d_in[9];
  const float* b_bond    = (const float*)d_in[10];
  const float* eW1 = (const float*)d_in[11];
  const float* eb1 = (const float*)d_in[12];
  const float* eW2 = (const float*)d_in[13];
  const float* eb2 = (const float*)d_in[14];
  const float* nW1 = (const float*)d_in[15];
  const float* nb1 = (const float*)d_in[16];
  const float* nW2 = (const float*)d_in[17];
  const float* nb2 = (const float*)d_in[18];
  const float* gam = (const float*)d_in[19];
  const float* bet = (const float*)d_in[20];
  const float* pW1 = (const float*)d_in[21];
  const float* pb1 = (const float*)d_in[22];
  const float* pW2 = (const float*)d_in[23];
  const float* pb2 = (const float*)d_in[24];
  const float* pW3 = (const float*)d_in[25];
  const float* pb3 = (const float*)d_in[26];

  int N = in_sizes[4];
  int E = in_sizes[3] / 2;
  int B = in_sizes[2];
  const int* row = eidx;
  const int* col = eidx + E;

  char* wptr = (char*)d_ws;
  unsigned short* ea16 = (unsigned short*)wptr; wptr += (((size_t)E * 64 * 2 + 255) & ~255ull);
  unsigned short* up16 = (unsigned short*)wptr; wptr += (((size_t)N * 128 * 2 + 255) & ~255ull);
  unsigned short* v16  = (unsigned short*)wptr; wptr += (((size_t)N * 64 * 2 + 255) & ~255ull);
  float* xemb = (float*)wptr; wptr += (size_t)N * 64 * 4;
  float* xnew = (float*)wptr; wptr += (size_t)N * 64 * 4;
  float* gbuf = (float*)wptr; wptr += (size_t)B * 64 * 4;
  float* bnacc = (float*)wptr; wptr += 256 * 4;
  int* counts = (int*)wptr;   wptr += (size_t)N * 4;
  int* scan_tmp = (int*)wptr; wptr += (size_t)N * 4;
  int* cursor = (int*)wptr;   wptr += (size_t)N * 4;
  int* bsum = (int*)wptr;     wptr += 4096;
  int* pos = (int*)wptr;      wptr += (size_t)E * 4;
  int* row_s = (int*)wptr;    wptr += (size_t)E * 4;
  int* col_s = (int*)wptr;    wptr += (size_t)E * 4;

  int NB = (N + 255) / 256;

  hipMemsetAsync(counts, 0, (size_t)N * 4, stream);
  k_hist<<<2048, 256, 0, stream>>>(col, counts, E);
  k_scan1<<<NB, 256, 0, stream>>>(counts, scan_tmp, bsum, N);
  k_scan2<<<1, 256, 0, stream>>>(bsum, NB);
  k_scan3<<<NB, 256, 0, stream>>>(counts, scan_tmp, bsum, cursor, N);
  k_scatter<<<2048, 256, 0, stream>>>(row, col, cursor, pos, row_s, col_s, E);

  k_embed_nodes<<<NB, 256, 0, stream>>>(x, batch, charge, W_charge, b_charge,
                                        W_atom, b_atom, xemb, N);
  k_embed_bonds_pos<<<4096, 256, 0, stream>>>(edge_attr, pos, W_bond, b_bond,
                                              ea16, E);

  int gridE = (E + 127) / 128;
  for (int i = 0; i < 3; ++i) {
    const float* leW1 = eW1 + (size_t)i * 192 * 64;
    const float* leb1 = eb1 + (size_t)i * 64;
    const float* leW2 = eW2 + (size_t)i * 64 * 64;
    const float* leb2 = eb2 + (size_t)i * 64;
    const float* lnW1 = nW1 + (size_t)i * 128 * 64;
    const float* lnb1 = nb1 + (size_t)i * 64;
    const float* lnW2 = nW2 + (size_t)i * 64 * 64;
    const float* lnb2 = nb2 + (size_t)i * 64;

    k_node_pre<<<NB, 256, 0, stream>>>(xemb, leW1, lnW1, up16, v16, N);
    hipMemsetAsync(xnew, 0, (size_t)N * 64 * 4, stream);
    hipMemsetAsync(bnacc, 0, 256 * 4, stream);
    k_edge_mfma<<<gridE, 256, 0, stream>>>(row_s, col_s, ea16, up16, v16,
                                           leW1 + 128 * 64, leb1, leW2, leb2,
                                           lnW1 + 64 * 64, lnb1, lnW2, lnb2,
                                           xnew, E);
    k_bn_stats<<<1024, 256, 0, stream>>>(xnew, bnacc, N);
    k_bn_apply<<<4096, 256, 0, stream>>>(xemb, xnew, bnacc, gam + (size_t)i * 64,
                                         bet + (size_t)i * 64, N);
  }

  k_pool<<<B, 256, 0, stream>>>(xemb, batch, N, gbuf);
  k_pred<<<B, 128, 0, stream>>>(gbuf, pW1, pb1, pW2, pb2, pW3, pb3, (float*)d_out);
}

// Round 5
// 2509.744 us; speedup vs baseline: 7.9630x; 1.0096x over previous
//
#include <hip/hip_runtime.h>
#include <math.h>

typedef short v8s __attribute__((ext_vector_type(8)));   // 8 bf16
typedef float v4f __attribute__((ext_vector_type(4)));

// fast softplus: max(x,0) + ln2*log2(1+exp(-|x|)); HW exp/log, ~3e-5 abs err
__device__ __forceinline__ float sp_f(float x) {
  return fmaxf(x, 0.0f) + 0.69314718056f * __log2f(1.0f + __expf(-fabsf(x)));
}

__device__ __forceinline__ unsigned short f2bf(float f) {
  union { float f; unsigned u; } x; x.f = f;
  unsigned r = (x.u + 0x7FFF + ((x.u >> 16) & 1)) >> 16;
  return (unsigned short)r;
}

__device__ __forceinline__ float bf2f(unsigned short h) {
  union { unsigned u; float f; } x; x.u = ((unsigned)h) << 16;
  return x.f;
}

// ---------------- one-shot weight fragment prep (3 layers x 4 mats) ----------------
// frag f: j=f&7, ln=(f>>3)&63, kh=(f>>9)&1, ct=f>>10
//   element W[kh*32 + (ln>>4)*8 + j][ct*16 + (ln&15)]
__global__ __launch_bounds__(256) void k_prep_wfrag(
    const float* __restrict__ eW1, const float* __restrict__ eW2,
    const float* __restrict__ nW1, const float* __restrict__ nW2,
    unsigned short* __restrict__ wfrag) {
  int i = blockIdx.x >> 2;   // layer
  int m = blockIdx.x & 3;    // matrix
  const float* W;
  if (m == 0)      W = eW1 + (size_t)i * 192 * 64 + 128 * 64;  // W1c
  else if (m == 1) W = eW2 + (size_t)i * 64 * 64;
  else if (m == 2) W = nW1 + (size_t)i * 128 * 64 + 64 * 64;   // nW1b
  else             W = nW2 + (size_t)i * 64 * 64;
  unsigned short* out = wfrag + ((size_t)i * 4 + m) * 4096;
  for (int f = threadIdx.x; f < 4096; f += 256) {
    int j = f & 7, ln = (f >> 3) & 63, kh = (f >> 9) & 1, ct = f >> 10;
    int k = kh * 32 + (ln >> 4) * 8 + j;
    int n = ct * 16 + (ln & 15);
    out[f] = f2bf(W[k * 64 + n]);
  }
}

// ---------------- node embedding (fp32) ----------------
__global__ __launch_bounds__(256) void k_embed_nodes(
    const float* __restrict__ x, const int* __restrict__ batch,
    const float* __restrict__ charge, const float* __restrict__ W_charge,
    const float* __restrict__ b_charge, const float* __restrict__ W_atom,
    const float* __restrict__ b_atom, float* __restrict__ xemb, int N) {
  __shared__ float sW[108 * 64];
  __shared__ float sb[64];
  __shared__ float sWc[16];
  __shared__ float sbc[16];
  for (int i = threadIdx.x; i < 108 * 64; i += blockDim.x) sW[i] = W_atom[i];
  if (threadIdx.x < 64) sb[threadIdx.x] = b_atom[threadIdx.x];
  if (threadIdx.x < 16) {
    sWc[threadIdx.x] = W_charge[threadIdx.x];
    sbc[threadIdx.x] = b_charge[threadIdx.x];
  }
  __syncthreads();
  int stride = gridDim.x * blockDim.x;
  for (int n = blockIdx.x * blockDim.x + threadIdx.x; n < N; n += stride) {
    float acc[64];
#pragma unroll
    for (int j = 0; j < 64; ++j) acc[j] = sb[j];
    const float* xr = x + (size_t)n * 92;
    for (int k = 0; k < 92; ++k) {
      float a = xr[k];
      const float* w = sW + k * 64;
#pragma unroll
      for (int j = 0; j < 64; ++j) acc[j] = fmaf(a, w[j], acc[j]);
    }
    float ch = charge[batch[n]];
#pragma unroll
    for (int c = 0; c < 16; ++c) {
      float cf = fmaf(ch, sWc[c], sbc[c]);
      const float* w = sW + (92 + c) * 64;
#pragma unroll
      for (int j = 0; j < 64; ++j) acc[j] = fmaf(cf, w[j], acc[j]);
    }
    float* o = xemb + (size_t)n * 64;
#pragma unroll
    for (int q = 0; q < 16; ++q)
      ((float4*)o)[q] = make_float4(acc[4*q], acc[4*q+1], acc[4*q+2], acc[4*q+3]);
  }
}

// ---------------- CSR build ----------------
__global__ __launch_bounds__(256) void k_hist(const int* __restrict__ col,
                                              int* __restrict__ counts, int E) {
  int stride = gridDim.x * blockDim.x;
  for (int e = blockIdx.x * blockDim.x + threadIdx.x; e < E; e += stride)
    atomicAdd(&counts[col[e]], 1);
}

__global__ __launch_bounds__(256) void k_scan1(const int* __restrict__ counts,
                                               int* __restrict__ scan_tmp,
                                               int* __restrict__ bsum, int N) {
  __shared__ int sd[2][256];
  int t = threadIdx.x;
  int i = blockIdx.x * 256 + t;
  int v = (i < N) ? counts[i] : 0;
  sd[0][t] = v;
  __syncthreads();
  int s = 0;
#pragma unroll
  for (int off = 1; off < 256; off <<= 1) {
    int nv = sd[s][t];
    if (t >= off) nv += sd[s][t - off];
    sd[s ^ 1][t] = nv;
    s ^= 1;
    __syncthreads();
  }
  if (i < N) scan_tmp[i] = sd[s][t];
  if (t == 255) bsum[blockIdx.x] = sd[s][255];
}

__global__ __launch_bounds__(256) void k_scan2(int* __restrict__ b, int NB) {
  __shared__ int sd[2][256];
  __shared__ int carry_s;
  int t = threadIdx.x;
  if (t == 0) carry_s = 0;
  __syncthreads();
  for (int base = 0; base < NB; base += 256) {
    int i = base + t;
    int v = (i < NB) ? b[i] : 0;
    sd[0][t] = v;
    __syncthreads();
    int s = 0;
#pragma unroll
    for (int off = 1; off < 256; off <<= 1) {
      int nv = sd[s][t];
      if (t >= off) nv += sd[s][t - off];
      sd[s ^ 1][t] = nv;
      s ^= 1;
      __syncthreads();
    }
    int c = carry_s;
    int tot = sd[s][255];
    if (i < NB) b[i] = sd[s][t] + c;
    __syncthreads();
    if (t == 0) carry_s = c + tot;
    __syncthreads();
  }
}

__global__ __launch_bounds__(256) void k_scan3(const int* __restrict__ counts,
                                               const int* __restrict__ scan_tmp,
                                               const int* __restrict__ bsum,
                                               int* __restrict__ cursor, int N) {
  int i = blockIdx.x * 256 + threadIdx.x;
  if (i < N) {
    int base = (blockIdx.x > 0) ? bsum[blockIdx.x - 1] : 0;
    cursor[i] = scan_tmp[i] - counts[i] + base;
  }
}

__global__ __launch_bounds__(256) void k_scatter(
    const int* __restrict__ row, const int* __restrict__ col,
    int* __restrict__ cursor, int* __restrict__ pos,
    int* __restrict__ row_s, int* __restrict__ col_s, int E) {
  int stride = gridDim.x * blockDim.x;
  for (int e = blockIdx.x * blockDim.x + threadIdx.x; e < E; e += stride) {
    int c = col[e];
    int p = atomicAdd(&cursor[c], 1);
    pos[e] = p;
    row_s[p] = row[e];
    col_s[p] = c;
  }
}

// ---------------- bond embedding: coalesced read, scatter write ----------------
__global__ __launch_bounds__(256) void k_embed_bonds_pos(
    const float* __restrict__ eattr, const int* __restrict__ pos,
    const float* __restrict__ W_bond, const float* __restrict__ b_bond,
    unsigned short* __restrict__ ea16, int E) {
  __shared__ float sW[41 * 64];
  __shared__ float sb[64];
  for (int i = threadIdx.x; i < 41 * 64; i += blockDim.x) sW[i] = W_bond[i];
  if (threadIdx.x < 64) sb[threadIdx.x] = b_bond[threadIdx.x];
  __syncthreads();
  int stride = gridDim.x * blockDim.x;
  for (int e = blockIdx.x * blockDim.x + threadIdx.x; e < E; e += stride) {
    float acc[64];
#pragma unroll
    for (int j = 0; j < 64; ++j) acc[j] = sb[j];
    const float* er = eattr + (size_t)e * 41;
    for (int k = 0; k < 41; ++k) {
      float a = er[k];
      const float* w = sW + k * 64;
#pragma unroll
      for (int j = 0; j < 64; ++j) acc[j] = fmaf(a, w[j], acc[j]);
    }
    size_t ob = (size_t)pos[e] * 64;
#pragma unroll
    for (int q8 = 0; q8 < 8; ++q8) {
      unsigned short tmp[8];
#pragma unroll
      for (int j = 0; j < 8; ++j) tmp[j] = f2bf(acc[q8 * 8 + j]);
      *(uint4*)&ea16[ob + q8 * 8] = *(uint4*)tmp;
    }
  }
}

// ---------------- node-side precompute body (shared by 2 kernels) ----------------
// storage permute: out[i] = val[((i&3)<<4) | (i>>2)] so lane c16 reads ushort4
__device__ __forceinline__ void node_pre_body(
    const float* __restrict__ xr, const float* sWa, const float* sWb,
    const float* sWp, unsigned short* __restrict__ up16,
    unsigned short* __restrict__ v16, int n) {
  const float4* xr4 = (const float4*)xr;
  float u[64], p[64];
#pragma unroll
  for (int j = 0; j < 64; ++j) { u[j] = 0.f; p[j] = 0.f; }
  for (int k4 = 0; k4 < 16; ++k4) {
    float4 av = xr4[k4];
    const float* wa = sWa + k4 * 256;
    const float* wp = sWp + k4 * 256;
#pragma unroll
    for (int j = 0; j < 64; ++j) u[j] = fmaf(av.x, wa[j], u[j]);
#pragma unroll
    for (int j = 0; j < 64; ++j) p[j] = fmaf(av.x, wp[j], p[j]);
#pragma unroll
    for (int j = 0; j < 64; ++j) u[j] = fmaf(av.y, wa[64 + j], u[j]);
#pragma unroll
    for (int j = 0; j < 64; ++j) p[j] = fmaf(av.y, wp[64 + j], p[j]);
#pragma unroll
    for (int j = 0; j < 64; ++j) u[j] = fmaf(av.z, wa[128 + j], u[j]);
#pragma unroll
    for (int j = 0; j < 64; ++j) p[j] = fmaf(av.z, wp[128 + j], p[j]);
#pragma unroll
    for (int j = 0; j < 64; ++j) u[j] = fmaf(av.w, wa[192 + j], u[j]);
#pragma unroll
    for (int j = 0; j < 64; ++j) p[j] = fmaf(av.w, wp[192 + j], p[j]);
  }
  unsigned short* o = up16 + (size_t)n * 128;
#pragma unroll
  for (int q8 = 0; q8 < 8; ++q8) {
    unsigned short tmp[8];
#pragma unroll
    for (int j = 0; j < 8; ++j) {
      int i = q8 * 8 + j;
      tmp[j] = f2bf(u[((i & 3) << 4) | (i >> 2)]);
    }
    *(uint4*)&o[q8 * 8] = *(uint4*)tmp;
  }
#pragma unroll
  for (int q8 = 0; q8 < 8; ++q8) {
    unsigned short tmp[8];
#pragma unroll
    for (int j = 0; j < 8; ++j) {
      int i = q8 * 8 + j;
      tmp[j] = f2bf(p[((i & 3) << 4) | (i >> 2)]);
    }
    *(uint4*)&o[64 + q8 * 8] = *(uint4*)tmp;
  }
  float vv[64];
#pragma unroll
  for (int j = 0; j < 64; ++j) vv[j] = 0.f;
  for (int k4 = 0; k4 < 16; ++k4) {
    float4 av = xr4[k4];
    const float* wb = sWb + k4 * 256;
#pragma unroll
    for (int j = 0; j < 64; ++j) vv[j] = fmaf(av.x, wb[j], vv[j]);
#pragma unroll
    for (int j = 0; j < 64; ++j) vv[j] = fmaf(av.y, wb[64 + j], vv[j]);
#pragma unroll
    for (int j = 0; j < 64; ++j) vv[j] = fmaf(av.z, wb[128 + j], vv[j]);
#pragma unroll
    for (int j = 0; j < 64; ++j) vv[j] = fmaf(av.w, wb[192 + j], vv[j]);
  }
  unsigned short* ov = v16 + (size_t)n * 64;
#pragma unroll
  for (int q8 = 0; q8 < 8; ++q8) {
    unsigned short tmp[8];
#pragma unroll
    for (int j = 0; j < 8; ++j) {
      int i = q8 * 8 + j;
      tmp[j] = f2bf(vv[((i & 3) << 4) | (i >> 2)]);
    }
    *(uint4*)&ov[q8 * 8] = *(uint4*)tmp;
  }
}

__global__ __launch_bounds__(256) void k_node_pre(
    const float* __restrict__ xemb, const float* __restrict__ eW1,
    const float* __restrict__ nW1, unsigned short* __restrict__ up16,
    unsigned short* __restrict__ v16, int N) {
  __shared__ float sWa[64 * 64];
  __shared__ float sWb[64 * 64];
  __shared__ float sWp[64 * 64];
  for (int i = threadIdx.x; i < 64 * 64; i += blockDim.x) {
    sWa[i] = eW1[i];
    sWb[i] = eW1[64 * 64 + i];
    sWp[i] = nW1[i];
  }
  __syncthreads();
  int stride = gridDim.x * blockDim.x;
  for (int n = blockIdx.x * blockDim.x + threadIdx.x; n < N; n += stride)
    node_pre_body(xemb + (size_t)n * 64, sWa, sWb, sWp, up16, v16, n);
}

// ---------------- fused BN apply + residual + next-layer node_pre ----------------
__global__ __launch_bounds__(256) void k_bn_pre(
    float* __restrict__ xemb, const float* __restrict__ xnew,
    const float* __restrict__ bnacc, const float* __restrict__ gamma,
    const float* __restrict__ beta, const float* __restrict__ eW1n,
    const float* __restrict__ nW1n, unsigned short* __restrict__ up16,
    unsigned short* __restrict__ v16, int N) {
  __shared__ float sWa[64 * 64];
  __shared__ float sWb[64 * 64];
  __shared__ float sWp[64 * 64];
  __shared__ float sscale[64], sshift[64];
  for (int i = threadIdx.x; i < 64 * 64; i += blockDim.x) {
    sWa[i] = eW1n[i];
    sWb[i] = eW1n[64 * 64 + i];
    sWp[i] = nW1n[i];
  }
  if (threadIdx.x < 64) {
    float inv = 1.0f / (float)N;
    float m = bnacc[threadIdx.x] * inv;
    float var = bnacc[64 + threadIdx.x] * inv - m * m;
    float rs = rsqrtf(var + 1e-5f);
    float g = gamma[threadIdx.x];
    sscale[threadIdx.x] = rs * g;
    sshift[threadIdx.x] = beta[threadIdx.x] - m * rs * g;
  }
  __syncthreads();
  int stride = gridDim.x * blockDim.x;
  for (int n = blockIdx.x * blockDim.x + threadIdx.x; n < N; n += stride) {
    float* xr = xemb + (size_t)n * 64;
    float xv[64];
#pragma unroll
    for (int q = 0; q < 16; ++q) {
      float4 xn4 = ((const float4*)(xnew + (size_t)n * 64))[q];
      float4 xo4 = ((const float4*)xr)[q];
      xv[4*q+0] = xo4.x + sp_f(fmaf(xn4.x, sscale[4*q+0], sshift[4*q+0]));
      xv[4*q+1] = xo4.y + sp_f(fmaf(xn4.y, sscale[4*q+1], sshift[4*q+1]));
      xv[4*q+2] = xo4.z + sp_f(fmaf(xn4.z, sscale[4*q+2], sshift[4*q+2]));
      xv[4*q+3] = xo4.w + sp_f(fmaf(xn4.w, sscale[4*q+3], sshift[4*q+3]));
      ((float4*)xr)[q] = make_float4(xv[4*q], xv[4*q+1], xv[4*q+2], xv[4*q+3]);
    }
    node_pre_body(xr, sWa, sWb, sWp, up16, v16, n);
  }
}

// ---------------- fused per-layer edge kernel, MFMA bf16 ----------------
#define READ_FRAGS(P)                                                        \
  {                                                                          \
    const v8s* wp_ = (const v8s*)gWf + (P) * 512;                            \
    _Pragma("unroll") for (int ct = 0; ct < 4; ++ct)                         \
        _Pragma("unroll") for (int kh = 0; kh < 2; ++kh)                     \
            bfr[ct][kh] = wp_[(ct * 2 + kh) * 64 + l];                       \
    _Pragma("unroll") for (int rb = 0; rb < 2; ++rb)                         \
        _Pragma("unroll") for (int kh = 0; kh < 2; ++kh) {                   \
      int row_ = rbase + rb * 16 + c16;                                      \
      af[rb][kh] = *(const v8s*)&sA[row_ * 64 +                              \
                                    ((kh * 32 + q * 8) ^ ((row_ & 7) << 3))];\
    }                                                                        \
  }

#define DO_MFMA()                                                            \
  _Pragma("unroll") for (int rb = 0; rb < 2; ++rb)                           \
      _Pragma("unroll") for (int ct = 0; ct < 4; ++ct) {                     \
    v4f a_ = {0.f, 0.f, 0.f, 0.f};                                           \
    a_ = __builtin_amdgcn_mfma_f32_16x16x32_bf16(af[rb][0], bfr[ct][0], a_,  \
                                                 0, 0, 0);                   \
    a_ = __builtin_amdgcn_mfma_f32_16x16x32_bf16(af[rb][1], bfr[ct][1], a_,  \
                                                 0, 0, 0);                   \
    acc[rb][ct] = a_;                                                        \
  }

__global__ __launch_bounds__(256, 4) void k_edge_mfma(
    const int* __restrict__ row_s, const int* __restrict__ col_s,
    unsigned short* __restrict__ ea16, const unsigned short* __restrict__ up16,
    const unsigned short* __restrict__ v16,
    const unsigned short* __restrict__ gWf, const float* __restrict__ eb1,
    const float* __restrict__ eb2, const float* __restrict__ nb1,
    const float* __restrict__ nb2, float* __restrict__ xnew, int E) {
  // LDS: msgb fp32 [128][64] = 32KB; sA bf16 [128][64] = 16KB aliases its
  // first half (sA dead after READ_FRAGS(3)+barrier). + biases + scol.
  __shared__ __align__(16) unsigned char smem[34304];
  unsigned short* sA = (unsigned short*)smem;             // 16 KB (aliased)
  float* msgb        = (float*)smem;                      // 32 KB
  float* sBb         = (float*)(smem + 32768);            // 1 KB
  int* scol          = (int*)(smem + 33792);              // 512 B

  int tid = threadIdx.x;
  int te = blockIdx.x * 128;

  if (tid < 64) {
    sBb[0 * 64 + tid] = eb1[tid];
    sBb[1 * 64 + tid] = eb2[tid];
    sBb[2 * 64 + tid] = nb1[tid];
    sBb[3 * 64 + tid] = nb2[tid];
  }
  if (tid < 128) {
    int e = te + tid;
    scol[tid] = col_s[e < E ? e : E - 1];
  }
  for (int i = tid; i < 1024; i += 256) {
    int r = i >> 3, cc = i & 7;
    int e = te + r;
    if (e >= E) e = E - 1;
    uint4 d = *(const uint4*)&ea16[(size_t)e * 64 + cc * 8];
    *(uint4*)&sA[r * 64 + ((cc * 8) ^ ((r & 7) << 3))] = d;
  }

  int w = tid >> 6, l = tid & 63, q = l >> 4, c16 = l & 15;
  int rbase = w * 32;

  int rid[2][4], cid[2][4], eid[2][4];
#pragma unroll
  for (int rb = 0; rb < 2; ++rb)
#pragma unroll
    for (int r = 0; r < 4; ++r) {
      int rit = rbase + rb * 16 + q * 4 + r;
      int e = te + rit;
      eid[rb][r] = e;
      int ec = e < E ? e : E - 1;
      rid[rb][r] = row_s[ec];
      cid[rb][r] = col_s[ec];
    }

  v8s af[2][2];
  v8s bfr[4][2];
  v4f acc[2][4];

  // ---- phase 0: T = sp(ea@W1c + b1 + u[row] + v[col]) ----
  __syncthreads();
  READ_FRAGS(0);
  __syncthreads();
  DO_MFMA();
#pragma unroll
  for (int rb = 0; rb < 2; ++rb)
#pragma unroll
    for (int r = 0; r < 4; ++r) {
      ushort4 uu = *(const ushort4*)&up16[(size_t)rid[rb][r] * 128 + c16 * 4];
      ushort4 vv = *(const ushort4*)&v16[(size_t)cid[rb][r] * 64 + c16 * 4];
      int row = rbase + rb * 16 + q * 4 + r;
      const unsigned short* up_ = (const unsigned short*)&uu;
      const unsigned short* vp_ = (const unsigned short*)&vv;
#pragma unroll
      for (int ct = 0; ct < 4; ++ct) {
        int n = ct * 16 + c16;
        float t = acc[rb][ct][r] + sBb[n] + bf2f(up_[ct]) + bf2f(vp_[ct]);
        t = sp_f(t);
        sA[row * 64 + (n ^ ((row & 7) << 3))] = f2bf(t);
      }
    }

  // ---- phase 1: ea' = T@eW2 + b2 -> sA, then coalesced writeback ----
  __syncthreads();
  READ_FRAGS(1);
  __syncthreads();
  DO_MFMA();
#pragma unroll
  for (int rb = 0; rb < 2; ++rb)
#pragma unroll
    for (int ct = 0; ct < 4; ++ct) {
      int n = ct * 16 + c16;
#pragma unroll
      for (int r = 0; r < 4; ++r) {
        float en = acc[rb][ct][r] + sBb[64 + n];
        int row = rbase + rb * 16 + q * 4 + r;
        sA[row * 64 + (n ^ ((row & 7) << 3))] = f2bf(en);
      }
    }
  __syncthreads();
  for (int i = tid; i < 1024; i += 256) {
    int r = i >> 3, cc = i & 7;
    if (te + r < E) {
      uint4 d = *(const uint4*)&sA[r * 64 + ((cc * 8) ^ ((r & 7) << 3))];
      *(uint4*)&ea16[(size_t)(te + r) * 64 + cc * 8] = d;
    }
  }

  // ---- phase 2: T2 = sp(ea'@nW1b + b3 + p[row]) ----
  READ_FRAGS(2);
  __syncthreads();
  DO_MFMA();
#pragma unroll
  for (int rb = 0; rb < 2; ++rb)
#pragma unroll
    for (int r = 0; r < 4; ++r) {
      ushort4 pp = *(const ushort4*)&up16[(size_t)rid[rb][r] * 128 + 64 + c16 * 4];
      int row = rbase + rb * 16 + q * 4 + r;
      const unsigned short* pp_ = (const unsigned short*)&pp;
#pragma unroll
      for (int ct = 0; ct < 4; ++ct) {
        int n = ct * 16 + c16;
        float t2 = acc[rb][ct][r] + sBb[128 + n] + bf2f(pp_[ct]);
        t2 = sp_f(t2);
        sA[row * 64 + (n ^ ((row & 7) << 3))] = f2bf(t2);
      }
    }

  // ---- phase 3: msg = T2@nW2 + b4 -> msgb (sA dead after frag loads) ----
  __syncthreads();
  READ_FRAGS(3);
  __syncthreads();   // all waves' af loaded; sA region reusable as msgb
  DO_MFMA();
#pragma unroll
  for (int rb = 0; rb < 2; ++rb)
#pragma unroll
    for (int ct = 0; ct < 4; ++ct) {
      int n = ct * 16 + c16;
#pragma unroll
      for (int r = 0; r < 4; ++r) {
        float msg = acc[rb][ct][r] + sBb[192 + n];
        int row = rbase + rb * 16 + q * 4 + r;
        msgb[row * 64 + n] = (eid[rb][r] < E) ? msg : 0.0f;
      }
    }
  __syncthreads();

  // ---- segmented reduction over col-runs; one atomic per (segment, channel) ----
  int nrows = E - te;
  if (nrows > 128) nrows = 128;
  for (int r0 = w; r0 < nrows; r0 += 4) {
    int c0 = scol[r0];
    if (r0 > 0 && scol[r0 - 1] == c0) continue;
    float s = 0.0f;
    int r = r0;
    do {
      s += msgb[r * 64 + l];
      ++r;
    } while (r < nrows && scol[r] == c0);
    atomicAdd(&xnew[(size_t)c0 * 64 + l], s);
  }
}

// ---------------- BN stats ----------------
__global__ __launch_bounds__(256) void k_bn_stats(
    const float* __restrict__ xnew, float* __restrict__ bnacc, int N) {
  int t = threadIdx.x;
  int ch = t & 63;
  int sl = t >> 6;
  float s = 0.f, s2 = 0.f;
  for (int n = blockIdx.x * 4 + sl; n < N; n += gridDim.x * 4) {
    float v = xnew[(size_t)n * 64 + ch];
    s += v;
    s2 = fmaf(v, v, s2);
  }
  __shared__ float red[256], red2[256];
  red[t] = s;
  red2[t] = s2;
  __syncthreads();
  if (sl == 0) {
    s = red[ch] + red[64 + ch] + red[128 + ch] + red[192 + ch];
    s2 = red2[ch] + red2[64 + ch] + red2[128 + ch] + red2[192 + ch];
    atomicAdd(&bnacc[ch], s);
    atomicAdd(&bnacc[64 + ch], s2);
  }
}

// ---------------- BN apply + softplus + residual (last layer) ----------------
__global__ __launch_bounds__(256) void k_bn_apply(
    float* __restrict__ x, const float* __restrict__ xnew,
    const float* __restrict__ bnacc, const float* __restrict__ gamma,
    const float* __restrict__ beta, int N) {
  __shared__ float sscale[64], sshift[64];
  if (threadIdx.x < 64) {
    float inv = 1.0f / (float)N;
    float m = bnacc[threadIdx.x] * inv;
    float var = bnacc[64 + threadIdx.x] * inv - m * m;
    float rs = rsqrtf(var + 1e-5f);
    float g = gamma[threadIdx.x];
    sscale[threadIdx.x] = rs * g;
    sshift[threadIdx.x] = beta[threadIdx.x] - m * rs * g;
  }
  __syncthreads();
  size_t total = (size_t)N * 64;
  size_t stride = (size_t)gridDim.x * blockDim.x;
  for (size_t i = (size_t)blockIdx.x * blockDim.x + threadIdx.x; i < total; i += stride) {
    int ch = (int)(i & 63);
    float v = fmaf(xnew[i], sscale[ch], sshift[ch]);
    x[i] += sp_f(v);
  }
}

// ---------------- fused pool + predictor: one block (256 thr) per graph ----------------
__device__ __forceinline__ int lbound(const int* a, int n, int key) {
  int lo = 0, hi = n;
  while (lo < hi) {
    int mid = (lo + hi) >> 1;
    if (a[mid] < key) lo = mid + 1; else hi = mid;
  }
  return lo;
}

__global__ __launch_bounds__(256) void k_pool_pred(
    const float* __restrict__ x, const int* __restrict__ batch, int N,
    const float* __restrict__ pW1, const float* __restrict__ pb1,
    const float* __restrict__ pW2, const float* __restrict__ pb2,
    const float* __restrict__ pW3, const float* __restrict__ pb3,
    float* __restrict__ out) {
  int b = blockIdx.x;
  int lo = lbound(batch, N, b);
  int hi = lbound(batch, N, b + 1);
  int t = threadIdx.x;
  int ch = t & 63;
  int sl = t >> 6;
  float s = 0.f;
  for (int n = lo + sl; n < hi; n += 4) s += x[(size_t)n * 64 + ch];
  __shared__ float red4[4][64];
  __shared__ float sg[64];
  __shared__ float sh1[128];
  __shared__ float red[128];
  red4[sl][ch] = s;
  __syncthreads();
  if (t < 64) {
    float tot = red4[0][t] + red4[1][t] + red4[2][t] + red4[3][t];
    float cnt = (float)(hi - lo);
    sg[t] = tot / fmaxf(cnt, 1.0f);
  }
  __syncthreads();
  if (t < 128) {
    float h = pb1[t];
    for (int k = 0; k < 64; ++k) h = fmaf(sg[k], pW1[k * 128 + t], h);
    sh1[t] = sp_f(h);
  }
  __syncthreads();
  if (t < 128) {
    float h = pb2[t];
    for (int k = 0; k < 128; ++k) h = fmaf(sh1[k], pW2[k * 128 + t], h);
    red[t] = sp_f(h) * pW3[t];
  }
  __syncthreads();
  for (int off = 64; off > 0; off >>= 1) {
    if (t < off) red[t] += red[t + off];
    __syncthreads();
  }
  if (t == 0) out[b] = red[0] + pb3[0];
}

extern "C" void kernel_launch(void* const* d_in, const int* in_sizes, int n_in,
                              void* d_out, int out_size, void* d_ws, size_t ws_size,
                              hipStream_t stream) {
  const float* x         = (const float*)d_in[0];
  const float* edge_attr = (const float*)d_in[1];
  const float* charge    = (const float*)d_in[2];
  const int*   eidx      = (const int*)d_in[3];
  const int*   batch     = (const int*)d_in[4];
  const float* W_charge  = (const float*)d_in[5];
  const float* b_charge  = (const float*)d_in[6];
  const float* W_atom    = (const float*)d_in[7];
  const float* b_atom    = (const float*)d_in[8];
  const float* W_bond    = (const float*)d_in[9];
  const float* b_bond    = (const float*)d_in[10];
  const float* eW1 = (const float*)d_in[11];
  const float* eb1 = (const float*)d_in[12];
  const float* eW2 = (const float*)d_in[13];
  const float* eb2 = (const float*)d_in[14];
  const float* nW1 = (const float*)d_in[15];
  const float* nb1 = (const float*)d_in[16];
  const float* nW2 = (const float*)d_in[17];
  const float* nb2 = (const float*)d_in[18];
  const float* gam = (const float*)d_in[19];
  const float* bet = (const float*)d_in[20];
  const float* pW1 = (const float*)d_in[21];
  const float* pb1 = (const float*)d_in[22];
  const float* pW2 = (const float*)d_in[23];
  const float* pb2 = (const float*)d_in[24];
  const float* pW3 = (const float*)d_in[25];
  const float* pb3 = (const float*)d_in[26];

  int N = in_sizes[4];
  int E = in_sizes[3] / 2;
  int B = in_sizes[2];
  const int* row = eidx;
  const int* col = eidx + E;

  char* wptr = (char*)d_ws;
  unsigned short* ea16 = (unsigned short*)wptr; wptr += (((size_t)E * 64 * 2 + 255) & ~255ull);
  unsigned short* up16 = (unsigned short*)wptr; wptr += (((size_t)N * 128 * 2 + 255) & ~255ull);
  unsigned short* v16  = (unsigned short*)wptr; wptr += (((size_t)N * 64 * 2 + 255) & ~255ull);
  unsigned short* wfrag = (unsigned short*)wptr; wptr += 12 * 4096 * 2;
  float* xemb = (float*)wptr; wptr += (size_t)N * 64 * 4;
  float* xnew = (float*)wptr; wptr += (size_t)N * 64 * 4;
  float* bnacc = (float*)wptr; wptr += 256 * 4;
  int* counts = (int*)wptr;   wptr += (size_t)N * 4;
  int* scan_tmp = (int*)wptr; wptr += (size_t)N * 4;
  int* cursor = (int*)wptr;   wptr += (size_t)N * 4;
  int* bsum = (int*)wptr;     wptr += 4096;
  int* pos = (int*)wptr;      wptr += (size_t)E * 4;
  int* row_s = (int*)wptr;    wptr += (size_t)E * 4;
  int* col_s = (int*)wptr;    wptr += (size_t)E * 4;

  int NB = (N + 255) / 256;

  k_prep_wfrag<<<12, 256, 0, stream>>>(eW1, eW2, nW1, nW2, wfrag);
  hipMemsetAsync(counts, 0, (size_t)N * 4, stream);
  k_hist<<<2048, 256, 0, stream>>>(col, counts, E);
  k_scan1<<<NB, 256, 0, stream>>>(counts, scan_tmp, bsum, N);
  k_scan2<<<1, 256, 0, stream>>>(bsum, NB);
  k_scan3<<<NB, 256, 0, stream>>>(counts, scan_tmp, bsum, cursor, N);
  k_scatter<<<2048, 256, 0, stream>>>(row, col, cursor, pos, row_s, col_s, E);

  k_embed_nodes<<<NB, 256, 0, stream>>>(x, batch, charge, W_charge, b_charge,
                                        W_atom, b_atom, xemb, N);
  k_embed_bonds_pos<<<4096, 256, 0, stream>>>(edge_attr, pos, W_bond, b_bond,
                                              ea16, E);
  k_node_pre<<<NB, 256, 0, stream>>>(xemb, eW1, nW1, up16, v16, N);

  int gridE = (E + 127) / 128;
  for (int i = 0; i < 3; ++i) {
    hipMemsetAsync(xnew, 0, (size_t)N * 64 * 4, stream);
    hipMemsetAsync(bnacc, 0, 256 * 4, stream);
    k_edge_mfma<<<gridE, 256, 0, stream>>>(
        row_s, col_s, ea16, up16, v16, wfrag + (size_t)i * 16384,
        eb1 + (size_t)i * 64, eb2 + (size_t)i * 64, nb1 + (size_t)i * 64,
        nb2 + (size_t)i * 64, xnew, E);
    k_bn_stats<<<1024, 256, 0, stream>>>(xnew, bnacc, N);
    if (i < 2) {
      k_bn_pre<<<NB, 256, 0, stream>>>(
          xemb, xnew, bnacc, gam + (size_t)i * 64, bet + (size_t)i * 64,
          eW1 + (size_t)(i + 1) * 192 * 64, nW1 + (size_t)(i + 1) * 128 * 64,
          up16, v16, N);
    } else {
      k_bn_apply<<<4096, 256, 0, stream>>>(xemb, xnew, bnacc,
                                           gam + (size_t)i * 64,
                                           bet + (size_t)i * 64, N);
    }
  }

  k_pool_pred<<<B, 256, 0, stream>>>(xemb, batch, N, pW1, pb1, pW2, pb2,
                                     pW3, pb3, (float*)d_out);
}

// Round 6
// 2198.009 us; speedup vs baseline: 9.0924x; 1.1418x over previous
//
#include <hip/hip_runtime.h>
#include <math.h>

typedef short v8s __attribute__((ext_vector_type(8)));   // 8 bf16
typedef float v4f __attribute__((ext_vector_type(4)));

// fast softplus: max(x,0) + ln2*log2(1+exp(-|x|)); HW exp/log, ~3e-5 abs err
__device__ __forceinline__ float sp_f(float x) {
  return fmaxf(x, 0.0f) + 0.69314718056f * __log2f(1.0f + __expf(-fabsf(x)));
}

__device__ __forceinline__ unsigned short f2bf(float f) {
  union { float f; unsigned u; } x; x.f = f;
  unsigned r = (x.u + 0x7FFF + ((x.u >> 16) & 1)) >> 16;
  return (unsigned short)r;
}

__device__ __forceinline__ float bf2f(unsigned short h) {
  union { unsigned u; float f; } x; x.u = ((unsigned)h) << 16;
  return x.f;
}

// ---------------- one-shot weight fragment prep (3 layers x 4 mats) ----------------
__global__ __launch_bounds__(256) void k_prep_wfrag(
    const float* __restrict__ eW1, const float* __restrict__ eW2,
    const float* __restrict__ nW1, const float* __restrict__ nW2,
    unsigned short* __restrict__ wfrag) {
  int i = blockIdx.x >> 2;   // layer
  int m = blockIdx.x & 3;    // matrix
  const float* W;
  if (m == 0)      W = eW1 + (size_t)i * 192 * 64 + 128 * 64;  // W1c
  else if (m == 1) W = eW2 + (size_t)i * 64 * 64;
  else if (m == 2) W = nW1 + (size_t)i * 128 * 64 + 64 * 64;   // nW1b
  else             W = nW2 + (size_t)i * 64 * 64;
  unsigned short* out = wfrag + ((size_t)i * 4 + m) * 4096;
  for (int f = threadIdx.x; f < 4096; f += 256) {
    int j = f & 7, ln = (f >> 3) & 63, kh = (f >> 9) & 1, ct = f >> 10;
    int k = kh * 32 + (ln >> 4) * 8 + j;
    int n = ct * 16 + (ln & 15);
    out[f] = f2bf(W[k * 64 + n]);
  }
}

// ---------------- node embedding, LDS-staged tiles + channel split ----------------
__global__ __launch_bounds__(256) void k_embed_nodes(
    const float* __restrict__ x, const int* __restrict__ batch,
    const float* __restrict__ charge, const float* __restrict__ W_charge,
    const float* __restrict__ b_charge, const float* __restrict__ W_atom,
    const float* __restrict__ b_atom, float* __restrict__ xemb, int N) {
  __shared__ float sW[108 * 64];   // 27.6 KB
  __shared__ float sX[128 * 92];   // 46 KB
  __shared__ float sb[64];
  __shared__ float sWc[16];
  __shared__ float sbc[16];
  for (int i = threadIdx.x; i < 108 * 64; i += blockDim.x) sW[i] = W_atom[i];
  if (threadIdx.x < 64) sb[threadIdx.x] = b_atom[threadIdx.x];
  if (threadIdx.x < 16) {
    sWc[threadIdx.x] = W_charge[threadIdx.x];
    sbc[threadIdx.x] = b_charge[threadIdx.x];
  }
  int ntiles = (N + 127) >> 7;
  for (int tile = blockIdx.x; tile < ntiles; tile += gridDim.x) {
    int base = tile << 7;
    int cnt = N - base; if (cnt > 128) cnt = 128;
    __syncthreads();   // protects sX reuse + first-iter sW staging
    if (cnt == 128) {
      const float4* src = (const float4*)(x + (size_t)base * 92);
      for (int i = threadIdx.x; i < 2944; i += 256) ((float4*)sX)[i] = src[i];
    } else {
      for (int i = threadIdx.x; i < cnt * 92; i += 256)
        sX[i] = x[(size_t)base * 92 + i];
    }
    __syncthreads();
    int t = threadIdx.x;
    int node = t & 127, half = t >> 7;
    if (node < cnt) {
      int n = base + node;
      float acc[32];
#pragma unroll
      for (int j = 0; j < 32; ++j) acc[j] = sb[half * 32 + j];
      const float* xr = sX + node * 92;
      for (int k = 0; k < 92; ++k) {
        float a = xr[k];
        const float* wk = sW + k * 64 + half * 32;
#pragma unroll
        for (int j = 0; j < 32; ++j) acc[j] = fmaf(a, wk[j], acc[j]);
      }
      float ch = charge[batch[n]];
#pragma unroll
      for (int c = 0; c < 16; ++c) {
        float cf = fmaf(ch, sWc[c], sbc[c]);
        const float* wk = sW + (92 + c) * 64 + half * 32;
#pragma unroll
        for (int j = 0; j < 32; ++j) acc[j] = fmaf(cf, wk[j], acc[j]);
      }
      float* o = xemb + (size_t)n * 64 + half * 32;
#pragma unroll
      for (int q8 = 0; q8 < 8; ++q8)
        ((float4*)o)[q8] = make_float4(acc[4*q8], acc[4*q8+1], acc[4*q8+2], acc[4*q8+3]);
    }
  }
}

// ---------------- CSR build ----------------
__global__ __launch_bounds__(256) void k_hist(const int* __restrict__ col,
                                              int* __restrict__ counts, int E) {
  int stride = gridDim.x * blockDim.x;
  for (int e = blockIdx.x * blockDim.x + threadIdx.x; e < E; e += stride)
    atomicAdd(&counts[col[e]], 1);
}

__global__ __launch_bounds__(256) void k_scan1(const int* __restrict__ counts,
                                               int* __restrict__ scan_tmp,
                                               int* __restrict__ bsum, int N) {
  __shared__ int sd[2][256];
  int t = threadIdx.x;
  int i = blockIdx.x * 256 + t;
  int v = (i < N) ? counts[i] : 0;
  sd[0][t] = v;
  __syncthreads();
  int s = 0;
#pragma unroll
  for (int off = 1; off < 256; off <<= 1) {
    int nv = sd[s][t];
    if (t >= off) nv += sd[s][t - off];
    sd[s ^ 1][t] = nv;
    s ^= 1;
    __syncthreads();
  }
  if (i < N) scan_tmp[i] = sd[s][t];
  if (t == 255) bsum[blockIdx.x] = sd[s][255];
}

__global__ __launch_bounds__(256) void k_scan2(int* __restrict__ b, int NB) {
  __shared__ int sd[2][256];
  __shared__ int carry_s;
  int t = threadIdx.x;
  if (t == 0) carry_s = 0;
  __syncthreads();
  for (int base = 0; base < NB; base += 256) {
    int i = base + t;
    int v = (i < NB) ? b[i] : 0;
    sd[0][t] = v;
    __syncthreads();
    int s = 0;
#pragma unroll
    for (int off = 1; off < 256; off <<= 1) {
      int nv = sd[s][t];
      if (t >= off) nv += sd[s][t - off];
      sd[s ^ 1][t] = nv;
      s ^= 1;
      __syncthreads();
    }
    int c = carry_s;
    int tot = sd[s][255];
    if (i < NB) b[i] = sd[s][t] + c;
    __syncthreads();
    if (t == 0) carry_s = c + tot;
    __syncthreads();
  }
}

__global__ __launch_bounds__(256) void k_scan3(const int* __restrict__ counts,
                                               const int* __restrict__ scan_tmp,
                                               const int* __restrict__ bsum,
                                               int* __restrict__ cursor, int N) {
  int i = blockIdx.x * 256 + threadIdx.x;
  if (i < N) {
    int base = (blockIdx.x > 0) ? bsum[blockIdx.x - 1] : 0;
    cursor[i] = scan_tmp[i] - counts[i] + base;
  }
}

__global__ __launch_bounds__(256) void k_scatter(
    const int* __restrict__ row, const int* __restrict__ col,
    int* __restrict__ cursor, int* __restrict__ pos,
    int* __restrict__ row_s, int* __restrict__ col_s, int E) {
  int stride = gridDim.x * blockDim.x;
  for (int e = blockIdx.x * blockDim.x + threadIdx.x; e < E; e += stride) {
    int c = col[e];
    int p = atomicAdd(&cursor[c], 1);
    pos[e] = p;
    row_s[p] = row[e];
    col_s[p] = c;
  }
}

// ---------------- bond embedding: LDS-staged tiles, scatter write ----------------
__global__ __launch_bounds__(256) void k_embed_bonds_pos(
    const float* __restrict__ eattr, const int* __restrict__ pos,
    const float* __restrict__ W_bond, const float* __restrict__ b_bond,
    unsigned short* __restrict__ ea16, int E) {
  __shared__ float sW[41 * 64];    // 10.5 KB
  __shared__ float sE[256 * 41];   // 42 KB
  __shared__ float sb[64];
  for (int i = threadIdx.x; i < 41 * 64; i += blockDim.x) sW[i] = W_bond[i];
  if (threadIdx.x < 64) sb[threadIdx.x] = b_bond[threadIdx.x];
  int ntiles = (E + 255) >> 8;
  for (int tile = blockIdx.x; tile < ntiles; tile += gridDim.x) {
    int base = tile << 8;
    int cnt = E - base; if (cnt > 256) cnt = 256;
    __syncthreads();
    if (cnt == 256) {
      const float4* src = (const float4*)(eattr + (size_t)base * 41);
      for (int i = threadIdx.x; i < 2624; i += 256) ((float4*)sE)[i] = src[i];
    } else {
      for (int i = threadIdx.x; i < cnt * 41; i += 256)
        sE[i] = eattr[(size_t)base * 41 + i];
    }
    __syncthreads();
    int t = threadIdx.x;
    if (t < cnt) {
      float acc[64];
#pragma unroll
      for (int j = 0; j < 64; ++j) acc[j] = sb[j];
      const float* er = sE + t * 41;
      for (int k = 0; k < 41; ++k) {
        float a = er[k];
        const float* wk = sW + k * 64;
#pragma unroll
        for (int j = 0; j < 64; ++j) acc[j] = fmaf(a, wk[j], acc[j]);
      }
      size_t ob = (size_t)pos[base + t] * 64;
#pragma unroll
      for (int q8 = 0; q8 < 8; ++q8) {
        unsigned short tmp[8];
#pragma unroll
        for (int j = 0; j < 8; ++j) tmp[j] = f2bf(acc[q8 * 8 + j]);
        *(uint4*)&ea16[ob + q8 * 8] = *(uint4*)tmp;
      }
    }
  }
}

// ---------------- node-side precompute body ----------------
// storage permute: out[i] = val[((i&3)<<4) | (i>>2)] so lane c16 reads ushort4
__device__ __forceinline__ void node_pre_body(
    const float* __restrict__ xr, const float* sWa, const float* sWb,
    const float* sWp, unsigned short* __restrict__ up16,
    unsigned short* __restrict__ v16, int n) {
  const float4* xr4 = (const float4*)xr;
  float u[64], p[64];
#pragma unroll
  for (int j = 0; j < 64; ++j) { u[j] = 0.f; p[j] = 0.f; }
  for (int k4 = 0; k4 < 16; ++k4) {
    float4 av = xr4[k4];
    const float* wa = sWa + k4 * 256;
    const float* wp = sWp + k4 * 256;
#pragma unroll
    for (int j = 0; j < 64; ++j) u[j] = fmaf(av.x, wa[j], u[j]);
#pragma unroll
    for (int j = 0; j < 64; ++j) p[j] = fmaf(av.x, wp[j], p[j]);
#pragma unroll
    for (int j = 0; j < 64; ++j) u[j] = fmaf(av.y, wa[64 + j], u[j]);
#pragma unroll
    for (int j = 0; j < 64; ++j) p[j] = fmaf(av.y, wp[64 + j], p[j]);
#pragma unroll
    for (int j = 0; j < 64; ++j) u[j] = fmaf(av.z, wa[128 + j], u[j]);
#pragma unroll
    for (int j = 0; j < 64; ++j) p[j] = fmaf(av.z, wp[128 + j], p[j]);
#pragma unroll
    for (int j = 0; j < 64; ++j) u[j] = fmaf(av.w, wa[192 + j], u[j]);
#pragma unroll
    for (int j = 0; j < 64; ++j) p[j] = fmaf(av.w, wp[192 + j], p[j]);
  }
  unsigned short* o = up16 + (size_t)n * 128;
#pragma unroll
  for (int q8 = 0; q8 < 8; ++q8) {
    unsigned short tmp[8];
#pragma unroll
    for (int j = 0; j < 8; ++j) {
      int i = q8 * 8 + j;
      tmp[j] = f2bf(u[((i & 3) << 4) | (i >> 2)]);
    }
    *(uint4*)&o[q8 * 8] = *(uint4*)tmp;
  }
#pragma unroll
  for (int q8 = 0; q8 < 8; ++q8) {
    unsigned short tmp[8];
#pragma unroll
    for (int j = 0; j < 8; ++j) {
      int i = q8 * 8 + j;
      tmp[j] = f2bf(p[((i & 3) << 4) | (i >> 2)]);
    }
    *(uint4*)&o[64 + q8 * 8] = *(uint4*)tmp;
  }
  float vv[64];
#pragma unroll
  for (int j = 0; j < 64; ++j) vv[j] = 0.f;
  for (int k4 = 0; k4 < 16; ++k4) {
    float4 av = xr4[k4];
    const float* wb = sWb + k4 * 256;
#pragma unroll
    for (int j = 0; j < 64; ++j) vv[j] = fmaf(av.x, wb[j], vv[j]);
#pragma unroll
    for (int j = 0; j < 64; ++j) vv[j] = fmaf(av.y, wb[64 + j], vv[j]);
#pragma unroll
    for (int j = 0; j < 64; ++j) vv[j] = fmaf(av.z, wb[128 + j], vv[j]);
#pragma unroll
    for (int j = 0; j < 64; ++j) vv[j] = fmaf(av.w, wb[192 + j], vv[j]);
  }
  unsigned short* ov = v16 + (size_t)n * 64;
#pragma unroll
  for (int q8 = 0; q8 < 8; ++q8) {
    unsigned short tmp[8];
#pragma unroll
    for (int j = 0; j < 8; ++j) {
      int i = q8 * 8 + j;
      tmp[j] = f2bf(vv[((i & 3) << 4) | (i >> 2)]);
    }
    *(uint4*)&ov[q8 * 8] = *(uint4*)tmp;
  }
}

__global__ __launch_bounds__(256) void k_node_pre(
    const float* __restrict__ xemb, const float* __restrict__ eW1,
    const float* __restrict__ nW1, unsigned short* __restrict__ up16,
    unsigned short* __restrict__ v16, int N) {
  __shared__ float sWa[64 * 64];
  __shared__ float sWb[64 * 64];
  __shared__ float sWp[64 * 64];
  for (int i = threadIdx.x; i < 64 * 64; i += blockDim.x) {
    sWa[i] = eW1[i];
    sWb[i] = eW1[64 * 64 + i];
    sWp[i] = nW1[i];
  }
  __syncthreads();
  int stride = gridDim.x * blockDim.x;
  for (int n = blockIdx.x * blockDim.x + threadIdx.x; n < N; n += stride)
    node_pre_body(xemb + (size_t)n * 64, sWa, sWb, sWp, up16, v16, n);
}

// ---------------- fused BN apply + residual + next-layer node_pre ----------------
__global__ __launch_bounds__(256) void k_bn_pre(
    float* __restrict__ xemb, const float* __restrict__ xnew,
    const float* __restrict__ bnacc, const float* __restrict__ gamma,
    const float* __restrict__ beta, const float* __restrict__ eW1n,
    const float* __restrict__ nW1n, unsigned short* __restrict__ up16,
    unsigned short* __restrict__ v16, int N) {
  __shared__ float sWa[64 * 64];
  __shared__ float sWb[64 * 64];
  __shared__ float sWp[64 * 64];
  __shared__ float sscale[64], sshift[64];
  for (int i = threadIdx.x; i < 64 * 64; i += blockDim.x) {
    sWa[i] = eW1n[i];
    sWb[i] = eW1n[64 * 64 + i];
    sWp[i] = nW1n[i];
  }
  if (threadIdx.x < 64) {
    float inv = 1.0f / (float)N;
    float m = bnacc[threadIdx.x] * inv;
    float var = bnacc[64 + threadIdx.x] * inv - m * m;
    float rs = rsqrtf(var + 1e-5f);
    float g = gamma[threadIdx.x];
    sscale[threadIdx.x] = rs * g;
    sshift[threadIdx.x] = beta[threadIdx.x] - m * rs * g;
  }
  __syncthreads();
  int stride = gridDim.x * blockDim.x;
  for (int n = blockIdx.x * blockDim.x + threadIdx.x; n < N; n += stride) {
    float* xr = xemb + (size_t)n * 64;
#pragma unroll
    for (int q = 0; q < 16; ++q) {
      float4 xn4 = ((const float4*)(xnew + (size_t)n * 64))[q];
      float4 xo4 = ((const float4*)xr)[q];
      xo4.x += sp_f(fmaf(xn4.x, sscale[4*q+0], sshift[4*q+0]));
      xo4.y += sp_f(fmaf(xn4.y, sscale[4*q+1], sshift[4*q+1]));
      xo4.z += sp_f(fmaf(xn4.z, sscale[4*q+2], sshift[4*q+2]));
      xo4.w += sp_f(fmaf(xn4.w, sscale[4*q+3], sshift[4*q+3]));
      ((float4*)xr)[q] = xo4;
    }
    node_pre_body(xr, sWa, sWb, sWp, up16, v16, n);
  }
}

// ---------------- fused per-layer edge kernel, MFMA bf16 ----------------
#define READ_FRAGS(P)                                                        \
  {                                                                          \
    const v8s* wp_ = (const v8s*)gWf + (P) * 512;                            \
    _Pragma("unroll") for (int ct = 0; ct < 4; ++ct)                         \
        _Pragma("unroll") for (int kh = 0; kh < 2; ++kh)                     \
            bfr[ct][kh] = wp_[(ct * 2 + kh) * 64 + l];                       \
    _Pragma("unroll") for (int rb = 0; rb < 2; ++rb)                         \
        _Pragma("unroll") for (int kh = 0; kh < 2; ++kh) {                   \
      int row_ = rbase + rb * 16 + c16;                                      \
      af[rb][kh] = *(const v8s*)&sA[row_ * 64 +                              \
                                    ((kh * 32 + q * 8) ^ ((row_ & 7) << 3))];\
    }                                                                        \
  }

#define DO_MFMA()                                                            \
  _Pragma("unroll") for (int rb = 0; rb < 2; ++rb)                           \
      _Pragma("unroll") for (int ct = 0; ct < 4; ++ct) {                     \
    v4f a_ = {0.f, 0.f, 0.f, 0.f};                                           \
    a_ = __builtin_amdgcn_mfma_f32_16x16x32_bf16(af[rb][0], bfr[ct][0], a_,  \
                                                 0, 0, 0);                   \
    a_ = __builtin_amdgcn_mfma_f32_16x16x32_bf16(af[rb][1], bfr[ct][1], a_,  \
                                                 0, 0, 0);                   \
    acc[rb][ct] = a_;                                                        \
  }

__global__ __launch_bounds__(256, 4) void k_edge_mfma(
    const int* __restrict__ row_s, const int* __restrict__ col_s,
    unsigned short* __restrict__ ea16, const unsigned short* __restrict__ up16,
    const unsigned short* __restrict__ v16,
    const unsigned short* __restrict__ gWf, const float* __restrict__ eb1,
    const float* __restrict__ eb2, const float* __restrict__ nb1,
    const float* __restrict__ nb2, float* __restrict__ xnew, int E) {
  __shared__ __align__(16) unsigned char smem[34304];
  unsigned short* sA = (unsigned short*)smem;             // 16 KB (aliased)
  float* msgb        = (float*)smem;                      // 32 KB
  float* sBb         = (float*)(smem + 32768);            // 1 KB
  int* scol          = (int*)(smem + 33792);              // 512 B

  int tid = threadIdx.x;
  int te = blockIdx.x * 128;
  int w = tid >> 6, l = tid & 63, q = l >> 4, c16 = l & 15;
  int rbase = w * 32;

  // gather indices first, then issue long-latency u/v prefetch
  int rid[2][4], cid[2][4], eid[2][4];
#pragma unroll
  for (int rb = 0; rb < 2; ++rb)
#pragma unroll
    for (int r = 0; r < 4; ++r) {
      int rit = rbase + rb * 16 + q * 4 + r;
      int e = te + rit;
      eid[rb][r] = e;
      int ec = e < E ? e : E - 1;
      rid[rb][r] = row_s[ec];
      cid[rb][r] = col_s[ec];
    }
  ushort4 uu_pf[2][4], vv_pf[2][4];
#pragma unroll
  for (int rb = 0; rb < 2; ++rb)
#pragma unroll
    for (int r = 0; r < 4; ++r) {
      uu_pf[rb][r] = *(const ushort4*)&up16[(size_t)rid[rb][r] * 128 + c16 * 4];
      vv_pf[rb][r] = *(const ushort4*)&v16[(size_t)cid[rb][r] * 64 + c16 * 4];
    }

  if (tid < 64) {
    sBb[0 * 64 + tid] = eb1[tid];
    sBb[1 * 64 + tid] = eb2[tid];
    sBb[2 * 64 + tid] = nb1[tid];
    sBb[3 * 64 + tid] = nb2[tid];
  }
  if (tid < 128) {
    int e = te + tid;
    scol[tid] = col_s[e < E ? e : E - 1];
  }
  for (int i = tid; i < 1024; i += 256) {
    int r = i >> 3, cc = i & 7;
    int e = te + r;
    if (e >= E) e = E - 1;
    uint4 d = *(const uint4*)&ea16[(size_t)e * 64 + cc * 8];
    *(uint4*)&sA[r * 64 + ((cc * 8) ^ ((r & 7) << 3))] = d;
  }

  v8s af[2][2];
  v8s bfr[4][2];
  v4f acc[2][4];

  __syncthreads();   // staging done (all rows)

  // ---- phase 0: T = sp(ea@W1c + b1 + u[row] + v[col]) ----
  READ_FRAGS(0);
  DO_MFMA();
  // prefetch p for phase 2 (lands during phase 1 + writeback)
  ushort4 pp_pf[2][4];
#pragma unroll
  for (int rb = 0; rb < 2; ++rb)
#pragma unroll
    for (int r = 0; r < 4; ++r)
      pp_pf[rb][r] =
          *(const ushort4*)&up16[(size_t)rid[rb][r] * 128 + 64 + c16 * 4];
#pragma unroll
  for (int rb = 0; rb < 2; ++rb)
#pragma unroll
    for (int r = 0; r < 4; ++r) {
      int row = rbase + rb * 16 + q * 4 + r;
      const unsigned short* up_ = (const unsigned short*)&uu_pf[rb][r];
      const unsigned short* vp_ = (const unsigned short*)&vv_pf[rb][r];
#pragma unroll
      for (int ct = 0; ct < 4; ++ct) {
        int n = ct * 16 + c16;
        float t = acc[rb][ct][r] + sBb[n] + bf2f(up_[ct]) + bf2f(vp_[ct]);
        t = sp_f(t);
        sA[row * 64 + (n ^ ((row & 7) << 3))] = f2bf(t);
      }
    }

  // ---- phase 1: ea' = T@eW2 + b2 -> sA (own band; in-wave order OK) ----
  READ_FRAGS(1);
  DO_MFMA();
#pragma unroll
  for (int rb = 0; rb < 2; ++rb)
#pragma unroll
    for (int ct = 0; ct < 4; ++ct) {
      int n = ct * 16 + c16;
#pragma unroll
      for (int r = 0; r < 4; ++r) {
        float en = acc[rb][ct][r] + sBb[64 + n];
        int row = rbase + rb * 16 + q * 4 + r;
        sA[row * 64 + (n ^ ((row & 7) << 3))] = f2bf(en);
      }
    }
  __syncthreads();   // writeback reads all rows
  for (int i = tid; i < 1024; i += 256) {
    int r = i >> 3, cc = i & 7;
    if (te + r < E) {
      uint4 d = *(const uint4*)&sA[r * 64 + ((cc * 8) ^ ((r & 7) << 3))];
      *(uint4*)&ea16[(size_t)(te + r) * 64 + cc * 8] = d;
    }
  }
  __syncthreads();   // epi2 writes must not race other waves' writeback reads

  // ---- phase 2: T2 = sp(ea'@nW1b + b3 + p[row]) ----
  READ_FRAGS(2);
  DO_MFMA();
#pragma unroll
  for (int rb = 0; rb < 2; ++rb)
#pragma unroll
    for (int r = 0; r < 4; ++r) {
      int row = rbase + rb * 16 + q * 4 + r;
      const unsigned short* pp_ = (const unsigned short*)&pp_pf[rb][r];
#pragma unroll
      for (int ct = 0; ct < 4; ++ct) {
        int n = ct * 16 + c16;
        float t2 = acc[rb][ct][r] + sBb[128 + n] + bf2f(pp_[ct]);
        t2 = sp_f(t2);
        sA[row * 64 + (n ^ ((row & 7) << 3))] = f2bf(t2);
      }
    }

  // ---- phase 3: msg = T2@nW2 + b4 -> msgb (sA dead after frag loads) ----
  READ_FRAGS(3);
  __syncthreads();   // all waves done reading sA; msgb alias safe
  DO_MFMA();
#pragma unroll
  for (int rb = 0; rb < 2; ++rb)
#pragma unroll
    for (int ct = 0; ct < 4; ++ct) {
      int n = ct * 16 + c16;
#pragma unroll
      for (int r = 0; r < 4; ++r) {
        float msg = acc[rb][ct][r] + sBb[192 + n];
        int row = rbase + rb * 16 + q * 4 + r;
        msgb[row * 64 + n] = (eid[rb][r] < E) ? msg : 0.0f;
      }
    }
  __syncthreads();

  // ---- segmented reduction; one atomic per (segment, channel) ----
  int nrows = E - te;
  if (nrows > 128) nrows = 128;
  for (int r0 = w; r0 < nrows; r0 += 4) {
    int c0 = scol[r0];
    if (r0 > 0 && scol[r0 - 1] == c0) continue;
    float s = 0.0f;
    int r = r0;
    do {
      s += msgb[r * 64 + l];
      ++r;
    } while (r < nrows && scol[r] == c0);
    atomicAdd(&xnew[(size_t)c0 * 64 + l], s);
  }
}

// ---------------- BN stats ----------------
__global__ __launch_bounds__(256) void k_bn_stats(
    const float* __restrict__ xnew, float* __restrict__ bnacc, int N) {
  int t = threadIdx.x;
  int ch = t & 63;
  int sl = t >> 6;
  float s = 0.f, s2 = 0.f;
  for (int n = blockIdx.x * 4 + sl; n < N; n += gridDim.x * 4) {
    float v = xnew[(size_t)n * 64 + ch];
    s += v;
    s2 = fmaf(v, v, s2);
  }
  __shared__ float red[256], red2[256];
  red[t] = s;
  red2[t] = s2;
  __syncthreads();
  if (sl == 0) {
    s = red[ch] + red[64 + ch] + red[128 + ch] + red[192 + ch];
    s2 = red2[ch] + red2[64 + ch] + red2[128 + ch] + red2[192 + ch];
    atomicAdd(&bnacc[ch], s);
    atomicAdd(&bnacc[64 + ch], s2);
  }
}

// ---------------- BN apply + softplus + residual (last layer) ----------------
__global__ __launch_bounds__(256) void k_bn_apply(
    float* __restrict__ x, const float* __restrict__ xnew,
    const float* __restrict__ bnacc, const float* __restrict__ gamma,
    const float* __restrict__ beta, int N) {
  __shared__ float sscale[64], sshift[64];
  if (threadIdx.x < 64) {
    float inv = 1.0f / (float)N;
    float m = bnacc[threadIdx.x] * inv;
    float var = bnacc[64 + threadIdx.x] * inv - m * m;
    float rs = rsqrtf(var + 1e-5f);
    float g = gamma[threadIdx.x];
    sscale[threadIdx.x] = rs * g;
    sshift[threadIdx.x] = beta[threadIdx.x] - m * rs * g;
  }
  __syncthreads();
  size_t total = (size_t)N * 64;
  size_t stride = (size_t)gridDim.x * blockDim.x;
  for (size_t i = (size_t)blockIdx.x * blockDim.x + threadIdx.x; i < total; i += stride) {
    int ch = (int)(i & 63);
    float v = fmaf(xnew[i], sscale[ch], sshift[ch]);
    x[i] += sp_f(v);
  }
}

// ---------------- fused pool + predictor ----------------
__device__ __forceinline__ int lbound(const int* a, int n, int key) {
  int lo = 0, hi = n;
  while (lo < hi) {
    int mid = (lo + hi) >> 1;
    if (a[mid] < key) lo = mid + 1; else hi = mid;
  }
  return lo;
}

__global__ __launch_bounds__(256) void k_pool_pred(
    const float* __restrict__ x, const int* __restrict__ batch, int N,
    const float* __restrict__ pW1, const float* __restrict__ pb1,
    const float* __restrict__ pW2, const float* __restrict__ pb2,
    const float* __restrict__ pW3, const float* __restrict__ pb3,
    float* __restrict__ out) {
  int b = blockIdx.x;
  int lo = lbound(batch, N, b);
  int hi = lbound(batch, N, b + 1);
  int t = threadIdx.x;
  int ch = t & 63;
  int sl = t >> 6;
  float s = 0.f;
  for (int n = lo + sl; n < hi; n += 4) s += x[(size_t)n * 64 + ch];
  __shared__ float red4[4][64];
  __shared__ float sg[64];
  __shared__ float sh1[128];
  __shared__ float red[128];
  red4[sl][ch] = s;
  __syncthreads();
  if (t < 64) {
    float tot = red4[0][t] + red4[1][t] + red4[2][t] + red4[3][t];
    float cnt = (float)(hi - lo);
    sg[t] = tot / fmaxf(cnt, 1.0f);
  }
  __syncthreads();
  if (t < 128) {
    float h = pb1[t];
    for (int k = 0; k < 64; ++k) h = fmaf(sg[k], pW1[k * 128 + t], h);
    sh1[t] = sp_f(h);
  }
  __syncthreads();
  if (t < 128) {
    float h = pb2[t];
    for (int k = 0; k < 128; ++k) h = fmaf(sh1[k], pW2[k * 128 + t], h);
    red[t] = sp_f(h) * pW3[t];
  }
  __syncthreads();
  for (int off = 64; off > 0; off >>= 1) {
    if (t < off) red[t] += red[t + off];
    __syncthreads();
  }
  if (t == 0) out[b] = red[0] + pb3[0];
}

extern "C" void kernel_launch(void* const* d_in, const int* in_sizes, int n_in,
                              void* d_out, int out_size, void* d_ws, size_t ws_size,
                              hipStream_t stream) {
  const float* x         = (const float*)d_in[0];
  const float* edge_attr = (const float*)d_in[1];
  const float* charge    = (const float*)d_in[2];
  const int*   eidx      = (const int*)d_in[3];
  const int*   batch     = (const int*)d_in[4];
  const float* W_charge  = (const float*)d_in[5];
  const float* b_charge  = (const float*)d_in[6];
  const float* W_atom    = (const float*)d_in[7];
  const float* b_atom    = (const float*)d_in[8];
  const float* W_bond    = (const float*)d_in[9];
  const float* b_bond    = (const float*)d_in[10];
  const float* eW1 = (const float*)d_in[11];
  const float* eb1 = (const float*)d_in[12];
  const float* eW2 = (const float*)d_in[13];
  const float* eb2 = (const float*)d_in[14];
  const float* nW1 = (const float*)d_in[15];
  const float* nb1 = (const float*)d_in[16];
  const float* nW2 = (const float*)d_in[17];
  const float* nb2 = (const float*)d_in[18];
  const float* gam = (const float*)d_in[19];
  const float* bet = (const float*)d_in[20];
  const float* pW1 = (const float*)d_in[21];
  const float* pb1 = (const float*)d_in[22];
  const float* pW2 = (const float*)d_in[23];
  const float* pb2 = (const float*)d_in[24];
  const float* pW3 = (const float*)d_in[25];
  const float* pb3 = (const float*)d_in[26];

  int N = in_sizes[4];
  int E = in_sizes[3] / 2;
  int B = in_sizes[2];
  const int* row = eidx;
  const int* col = eidx + E;

  char* wptr = (char*)d_ws;
  unsigned short* ea16 = (unsigned short*)wptr; wptr += (((size_t)E * 64 * 2 + 255) & ~255ull);
  unsigned short* up16 = (unsigned short*)wptr; wptr += (((size_t)N * 128 * 2 + 255) & ~255ull);
  unsigned short* v16  = (unsigned short*)wptr; wptr += (((size_t)N * 64 * 2 + 255) & ~255ull);
  unsigned short* wfrag = (unsigned short*)wptr; wptr += 12 * 4096 * 2;
  float* xemb = (float*)wptr; wptr += (size_t)N * 64 * 4;
  float* xnew = (float*)wptr; wptr += (size_t)N * 64 * 4;
  float* bnacc = (float*)wptr; wptr += 256 * 4;
  int* counts = (int*)wptr;   wptr += (size_t)N * 4;
  int* scan_tmp = (int*)wptr; wptr += (size_t)N * 4;
  int* cursor = (int*)wptr;   wptr += (size_t)N * 4;
  int* bsum = (int*)wptr;     wptr += 4096;
  int* pos = (int*)wptr;      wptr += (size_t)E * 4;
  int* row_s = (int*)wptr;    wptr += (size_t)E * 4;
  int* col_s = (int*)wptr;    wptr += (size_t)E * 4;

  int NB = (N + 255) / 256;

  k_prep_wfrag<<<12, 256, 0, stream>>>(eW1, eW2, nW1, nW2, wfrag);
  hipMemsetAsync(counts, 0, (size_t)N * 4, stream);
  k_hist<<<2048, 256, 0, stream>>>(col, counts, E);
  k_scan1<<<NB, 256, 0, stream>>>(counts, scan_tmp, bsum, N);
  k_scan2<<<1, 256, 0, stream>>>(bsum, NB);
  k_scan3<<<NB, 256, 0, stream>>>(counts, scan_tmp, bsum, cursor, N);
  k_scatter<<<2048, 256, 0, stream>>>(row, col, cursor, pos, row_s, col_s, E);

  int ntilesN = (N + 127) / 128;
  k_embed_nodes<<<ntilesN, 256, 0, stream>>>(x, batch, charge, W_charge,
                                             b_charge, W_atom, b_atom, xemb, N);
  k_embed_bonds_pos<<<2048, 256, 0, stream>>>(edge_attr, pos, W_bond, b_bond,
                                              ea16, E);
  k_node_pre<<<NB, 256, 0, stream>>>(xemb, eW1, nW1, up16, v16, N);

  int gridE = (E + 127) / 128;
  for (int i = 0; i < 3; ++i) {
    hipMemsetAsync(xnew, 0, (size_t)N * 64 * 4, stream);
    hipMemsetAsync(bnacc, 0, 256 * 4, stream);
    k_edge_mfma<<<gridE, 256, 0, stream>>>(
        row_s, col_s, ea16, up16, v16, wfrag + (size_t)i * 16384,
        eb1 + (size_t)i * 64, eb2 + (size_t)i * 64, nb1 + (size_t)i * 64,
        nb2 + (size_t)i * 64, xnew, E);
    k_bn_stats<<<1024, 256, 0, stream>>>(xnew, bnacc, N);
    if (i < 2) {
      k_bn_pre<<<NB, 256, 0, stream>>>(
          xemb, xnew, bnacc, gam + (size_t)i * 64, bet + (size_t)i * 64,
          eW1 + (size_t)(i + 1) * 192 * 64, nW1 + (size_t)(i + 1) * 128 * 64,
          up16, v16, N);
    } else {
      k_bn_apply<<<4096, 256, 0, stream>>>(xemb, xnew, bnacc,
                                           gam + (size_t)i * 64,
                                           bet + (size_t)i * 64, N);
    }
  }

  k_pool_pred<<<B, 256, 0, stream>>>(xemb, batch, N, pW1, pb1, pW2, pb2,
                                     pW3, pb3, (float*)d_out);
}